// Round 9
// baseline (121.405 us; speedup 1.0000x reference)
//
#include <hip/hip_runtime.h>
#include <hip/hip_fp16.h>

// ---------------------------------------------------------------------------
// GAT policy module: 2x GAT layer (head-mean) + mean-pool + 2 MLP heads.
// Round 24: gat1 restructured for gather concurrency. Budget (measured,
// R21/R22 attribution + R23 residual): fused ell+gemm1 41us | gat1 ~37 |
// gat2 ~21 | gemm2 3 | pool 1.5 | zero 1.
// gat1 theory: 340k x 256B gathers, mostly L2/L3-hit (whole-pipeline FETCH
// only 59MB), at 2.4TB/s effective = 7% of L2 BW -> latency/concurrency
// bound, not BW. Old layout: 2 nodes/wave, 32 lanes x 8B, 8 edges in
// flight per half-wave; 10k waves (> 8192 residency).
// NEW gat1_v2: 4 nodes/wave, 16 lanes x uint4 (16B) per edge -> 2x edges
// in flight per wave, half the load instrs, 5000 waves (fully resident).
// Lane map: head = l16>>2, ch-block = (l16&3)*16; head-mean via
// shfl_xor(4)+shfl_xor(8); lanes l16<4 store 16ch each.
// R23 kept: deg16 (padded counters), fused ell_gemm1 (GEMM blocks first),
// gemm1_v2 A-staged-once. Layer-2 gat/gemm2/pool unchanged (controls).
// MFMA fragment layouts (HW-verified): A[m=lane&15][k=quad*8+j],
// B[k=quad*8+j][n=lane&15], C/D col=lane&15, row=quad*4+reg.
// ---------------------------------------------------------------------------

#define G_GRAPHS 64

using half8   = __attribute__((ext_vector_type(8))) _Float16;
using half4v  = __attribute__((ext_vector_type(4))) _Float16;
using floatx4 = __attribute__((ext_vector_type(4))) float;
using floatx2 = __attribute__((ext_vector_type(2))) float;

// ---------------------------------------------------------------------------
__global__ __launch_bounds__(256) void zero_deg(int4* __restrict__ deg4, int n4)
{
    int i = blockIdx.x * 256 + threadIdx.x;
    if (i < n4) deg4[i] = int4{0, 0, 0, 0};
}

// ---------------------------------------------------------------------------
// FUSED: layer-1 GEMM v2 (blocks [0,mb)) + ELL build (blocks [mb,mb+eb)).
// ---------------------------------------------------------------------------
__global__ __launch_bounds__(256) void ell_gemm1(
        const int* __restrict__ ei, int* __restrict__ deg16,
        int* __restrict__ col_ell, int E0, int Etot, int mb,
        const float* __restrict__ A, const float* __restrict__ B,
        unsigned char* __restrict__ C8, const float* __restrict__ att_s,
        const float* __restrict__ att_d, float* __restrict__ a_s,
        float* __restrict__ a_d, int M)
{
    __shared__ _Float16 As[64][136];
    __shared__ _Float16 Bt[64][136];

    if ((int)blockIdx.x >= mb) {
        int idx = ((int)blockIdx.x - mb) * 256 + threadIdx.x;
        if (idx < Etot) {
            int src = (idx < E0) ? ei[idx]      : (idx - E0);
            int dst = (idx < E0) ? ei[E0 + idx] : (idx - E0);
            int slot = atomicAdd(&deg16[dst << 4], 1);
            if (slot < 64)
                col_ell[(size_t)dst * 64 + slot] = src;
        }
        return;
    }

    const int tid  = threadIdx.x;
    const int row0 = blockIdx.x * 64;
    const int wid  = tid >> 6;
    const int lane = tid & 63;
    const int r    = lane & 15;
    const int quad = lane >> 4;
    const int rw0  = wid * 16;

    const int arow = tid >> 2;
    const int akc  = (tid & 3) * 32;
    const int agr  = row0 + arow;

    #pragma unroll
    for (int i = 0; i < 4; i++) {
        half8 v = {};
        if (agr < M) {
            const float* p = &A[(size_t)agr * 128 + akc + i * 8];
            float4 f0 = *reinterpret_cast<const float4*>(p);
            float4 f1 = *reinterpret_cast<const float4*>(p + 4);
            v[0] = (_Float16)f0.x; v[1] = (_Float16)f0.y;
            v[2] = (_Float16)f0.z; v[3] = (_Float16)f0.w;
            v[4] = (_Float16)f1.x; v[5] = (_Float16)f1.y;
            v[6] = (_Float16)f1.z; v[7] = (_Float16)f1.w;
        }
        *reinterpret_cast<half8*>(&As[arow][akc + i * 8]) = v;
    }

    for (int by = 0; by < 4; by++) {
        __syncthreads();

        #pragma unroll
        for (int i = 0; i < 8; i++) {
            int id = tid + 256 * i;
            int k  = id >> 4;
            int n4 = (id & 15) * 4;
            float4 f = *reinterpret_cast<const float4*>(
                &B[(size_t)k * 256 + by * 64 + n4]);
            Bt[n4 + 0][k] = (_Float16)f.x;
            Bt[n4 + 1][k] = (_Float16)f.y;
            Bt[n4 + 2][k] = (_Float16)f.z;
            Bt[n4 + 3][k] = (_Float16)f.w;
        }
        __syncthreads();

        floatx4 acc[4] = {};
        #pragma unroll
        for (int s = 0; s < 4; s++) {
            half8 af = *reinterpret_cast<const half8*>(&As[rw0 + r][s * 32 + quad * 8]);
            #pragma unroll
            for (int nt = 0; nt < 4; nt++) {
                half8 bf = *reinterpret_cast<const half8*>(&Bt[nt * 16 + r][s * 32 + quad * 8]);
                acc[nt] = __builtin_amdgcn_mfma_f32_16x16x32_f16(af, bf, acc[nt], 0, 0, 0);
            }
        }

        float ps[4], pd[4];
        #pragma unroll
        for (int reg = 0; reg < 4; reg++) { ps[reg] = 0.f; pd[reg] = 0.f; }
        #pragma unroll
        for (int nt = 0; nt < 4; nt++) {
            int cl = nt * 16 + r;
            float ws = att_s[by * 64 + cl];
            float wd = att_d[by * 64 + cl];
            #pragma unroll
            for (int reg = 0; reg < 4; reg++) {
                ps[reg] += acc[nt][reg] * ws;
                pd[reg] += acc[nt][reg] * wd;
            }
        }
        #pragma unroll
        for (int off = 1; off < 16; off <<= 1)
            #pragma unroll
            for (int reg = 0; reg < 4; reg++) {
                ps[reg] += __shfl_xor(ps[reg], off);
                pd[reg] += __shfl_xor(pd[reg], off);
            }
        if (r == 0) {
            #pragma unroll
            for (int reg = 0; reg < 4; reg++) {
                int gr = row0 + rw0 + quad * 4 + reg;
                if (gr < M) {
                    a_s[gr * 4 + by] = ps[reg];
                    a_d[gr * 4 + by] = pd[reg];
                }
            }
        }

        __syncthreads();
        unsigned char (*lds8)[80] = reinterpret_cast<unsigned char(*)[80]>(&Bt[0][0]);
        #pragma unroll
        for (int nt = 0; nt < 4; nt++) {
            #pragma unroll
            for (int reg = 0; reg < 4; reg++) {
                int wv = __builtin_amdgcn_cvt_pk_fp8_f32(
                    acc[nt][reg], acc[nt][reg], 0, false);
                lds8[rw0 + quad * 4 + reg][nt * 16 + r] = (unsigned char)(wv & 0xFF);
            }
        }
        __syncthreads();
        {
            int row = tid >> 2;
            int c16 = (tid & 3) * 16;
            int gr  = row0 + row;
            if (gr < M) {
                int4 v = *reinterpret_cast<const int4*>(&lds8[row][c16]);
                *reinterpret_cast<int4*>(&C8[(size_t)gr * 256 + by * 64 + c16]) = v;
            }
        }
    }
}

// ---------------------------------------------------------------------------
// GEMM tile body (device fn) - used by gemm2 only (K=64, fp16 A, fp32 B).
// ---------------------------------------------------------------------------
template<int K, int HPB, bool A_FP32, bool B_FP32>
__device__ __forceinline__ void gemm_att_tile(
        const void* __restrict__ A_v, const void* __restrict__ B_v,
        void* __restrict__ C_out, const float* __restrict__ att_s,
        const float* __restrict__ att_d, float* __restrict__ a_s,
        float* __restrict__ a_d, int M, int Ntot, int Htot,
        int row0, int col0, int by,
        _Float16 (*As)[K + 8], _Float16 (*Bt)[K + 8])
{
    constexpr int CPH = 64 / HPB;
    constexpr int NTH = 4 / HPB;
    const int tid = threadIdx.x;

    {
        int row = tid >> 2;
        int kc  = (tid & 3) * (K / 4);
        int gr  = row0 + row;
        #pragma unroll
        for (int i = 0; i < K / 32; i++) {
            half8 v = {};
            if (gr < M) {
                if constexpr (A_FP32) {
                    const float* Af = (const float*)A_v;
                    float4 f0 = *reinterpret_cast<const float4*>(&Af[(size_t)gr * K + kc + i * 8]);
                    float4 f1 = *reinterpret_cast<const float4*>(&Af[(size_t)gr * K + kc + i * 8 + 4]);
                    v[0] = (_Float16)f0.x; v[1] = (_Float16)f0.y;
                    v[2] = (_Float16)f0.z; v[3] = (_Float16)f0.w;
                    v[4] = (_Float16)f1.x; v[5] = (_Float16)f1.y;
                    v[6] = (_Float16)f1.z; v[7] = (_Float16)f1.w;
                } else {
                    const _Float16* Ah = (const _Float16*)A_v;
                    v = *reinterpret_cast<const half8*>(&Ah[(size_t)gr * K + kc + i * 8]);
                }
            }
            *reinterpret_cast<half8*>(&As[row][kc + i * 8]) = v;
        }
    }
    {
        #pragma unroll
        for (int i = 0; i < K / 16; i++) {
            int id = tid + 256 * i;
            int k  = id >> 4;
            int n4 = (id & 15) * 4;
            _Float16 b0, b1, b2, b3;
            if constexpr (B_FP32) {
                const float* Bf = (const float*)B_v;
                float4 f = *reinterpret_cast<const float4*>(&Bf[(size_t)k * Ntot + col0 + n4]);
                b0 = (_Float16)f.x; b1 = (_Float16)f.y;
                b2 = (_Float16)f.z; b3 = (_Float16)f.w;
            } else {
                const _Float16* Bh = (const _Float16*)B_v;
                half4v v = *reinterpret_cast<const half4v*>(&Bh[(size_t)k * Ntot + col0 + n4]);
                b0 = v[0]; b1 = v[1]; b2 = v[2]; b3 = v[3];
            }
            Bt[n4 + 0][k] = b0; Bt[n4 + 1][k] = b1;
            Bt[n4 + 2][k] = b2; Bt[n4 + 3][k] = b3;
        }
    }
    __syncthreads();

    const int wid  = tid >> 6;
    const int lane = tid & 63;
    const int r    = lane & 15;
    const int quad = lane >> 4;
    const int rw0  = wid * 16;

    floatx4 acc[4] = {};
    #pragma unroll
    for (int s = 0; s < K / 32; s++) {
        half8 af = *reinterpret_cast<const half8*>(&As[rw0 + r][s * 32 + quad * 8]);
        #pragma unroll
        for (int nt = 0; nt < 4; nt++) {
            half8 bf = *reinterpret_cast<const half8*>(&Bt[nt * 16 + r][s * 32 + quad * 8]);
            acc[nt] = __builtin_amdgcn_mfma_f32_16x16x32_f16(af, bf, acc[nt], 0, 0, 0);
        }
    }

    float ps[HPB][4], pd[HPB][4];
    #pragma unroll
    for (int hl = 0; hl < HPB; hl++)
        #pragma unroll
        for (int reg = 0; reg < 4; reg++) { ps[hl][reg] = 0.f; pd[hl][reg] = 0.f; }

    #pragma unroll
    for (int nt = 0; nt < 4; nt++) {
        int hl = nt / NTH;
        int cl = (nt % NTH) * 16 + r;
        int hglob = by * HPB + hl;
        float ws = att_s[hglob * CPH + cl];
        float wd = att_d[hglob * CPH + cl];
        #pragma unroll
        for (int reg = 0; reg < 4; reg++) {
            ps[hl][reg] += acc[nt][reg] * ws;
            pd[hl][reg] += acc[nt][reg] * wd;
        }
    }
    #pragma unroll
    for (int off = 1; off < 16; off <<= 1)
        #pragma unroll
        for (int hl = 0; hl < HPB; hl++)
            #pragma unroll
            for (int reg = 0; reg < 4; reg++) {
                ps[hl][reg] += __shfl_xor(ps[hl][reg], off);
                pd[hl][reg] += __shfl_xor(pd[hl][reg], off);
            }
    if (r == 0) {
        #pragma unroll
        for (int reg = 0; reg < 4; reg++) {
            int gr = row0 + rw0 + quad * 4 + reg;
            if (gr < M) {
                #pragma unroll
                for (int hl = 0; hl < HPB; hl++) {
                    int hglob = by * HPB + hl;
                    a_s[gr * Htot + hglob] = ps[hl][reg];
                    a_d[gr * Htot + hglob] = pd[hl][reg];
                }
            }
        }
    }

    _Float16* Ch = (_Float16*)C_out;
    #pragma unroll
    for (int nt = 0; nt < 4; nt++) {
        #pragma unroll
        for (int reg = 0; reg < 4; reg++) {
            int gr = row0 + rw0 + quad * 4 + reg;
            if (gr < M)
                Ch[(size_t)gr * Ntot + col0 + nt * 16 + r] = (_Float16)acc[nt][reg];
        }
    }
}

// ---------------------------------------------------------------------------
__global__ __launch_bounds__(256) void gemm2_kernel(
        const _Float16* __restrict__ A, const float* __restrict__ B,
        _Float16* __restrict__ Ch, const float* __restrict__ att_s,
        const float* __restrict__ att_d, float* __restrict__ a_s,
        float* __restrict__ a_d, int M)
{
    __shared__ _Float16 As[64][72];
    __shared__ _Float16 Bt[64][72];
    gemm_att_tile<64, 2, false, true>(
        A, B, Ch, att_s, att_d, a_s, a_d,
        M, 64, 2, blockIdx.x * 64, 0, 0, As, Bt);
}

// ---------------------------------------------------------------------------
// FMA helpers.
// ---------------------------------------------------------------------------
__device__ inline void facc4_h(float* a, float2 raw, float p) {
    __half2 h0 = *reinterpret_cast<__half2*>(&raw.x);
    __half2 h1 = *reinterpret_cast<__half2*>(&raw.y);
    float2 f0 = __half22float2(h0), f1 = __half22float2(h1);
    a[0] += p * f0.x; a[1] += p * f0.y; a[2] += p * f1.x; a[3] += p * f1.y;
}
__device__ inline void facc4_8(float* a, unsigned int w, float p) {
    floatx2 lo = __builtin_amdgcn_cvt_pk_f32_fp8((int)w, false);
    floatx2 hi = __builtin_amdgcn_cvt_pk_f32_fp8((int)w, true);
    a[0] += p * lo[0]; a[1] += p * lo[1]; a[2] += p * hi[0]; a[3] += p * hi[1];
}
__device__ inline void facc8_8(float* a, uint2 w, float p) {
    facc4_8(a,     w.x, p);
    facc4_8(a + 4, w.y, p);
}
__device__ inline void facc16_8(float* a, uint4 w, float p) {
    facc4_8(a,      w.x, p);
    facc4_8(a + 4,  w.y, p);
    facc4_8(a + 8,  w.z, p);
    facc4_8(a + 12, w.w, p);
}

// ---------------------------------------------------------------------------
// General path (32 < deg <= 64, rare): full-wave per-node, max-subtraction.
// ---------------------------------------------------------------------------
template<int H, int C, bool OUT_HALF, bool FEAT_FP8>
__device__ void gat_general(
        int d, int lo, int degc, const int* __restrict__ colidx,
        const void* __restrict__ hfeat_v, const float* __restrict__ a_s,
        const float* __restrict__ a_d, const float* __restrict__ bias,
        void* __restrict__ out_v, int N, float* p_wave)
{
    if (d >= N) return;
    constexpr int FV = (H * C) / 64;
    const int lane = threadIdx.x & 63;
    const int hi = lo + degc;
    const __half* hfeat = (const __half*)hfeat_v;
    const unsigned char* ffeat = (const unsigned char*)hfeat_v;
    const int h_lane = (lane * FV) / C;

    float adp[H];
    #pragma unroll
    for (int h = 0; h < H; h++) adp[h] = a_d[d * H + h];
    float lh[H];
    #pragma unroll
    for (int h = 0; h < H; h++) lh[h] = 0.f;
    float acc[FV];
    #pragma unroll
    for (int v = 0; v < FV; v++) acc[v] = 0.f;

    float mh[H];
    #pragma unroll
    for (int h = 0; h < H; h++) mh[h] = -3.0e38f;
    for (int i = lo + lane; i < hi; i += 64) {
        int s = colidx[i];
        #pragma unroll
        for (int h = 0; h < H; h++) {
            float v = a_s[s * H + h] + adp[h];
            v = (v > 0.f) ? v : 0.2f * v;
            mh[h] = fmaxf(mh[h], v);
        }
    }
    #pragma unroll
    for (int off = 1; off < 64; off <<= 1)
        #pragma unroll
        for (int h = 0; h < H; h++)
            mh[h] = fmaxf(mh[h], __shfl_xor(mh[h], off));

    for (int base = lo; base < hi; base += 64) {
        int i = base + lane;
        int s = 0;
        if (i < hi) {
            s = colidx[i];
            #pragma unroll
            for (int h = 0; h < H; h++) {
                float v = a_s[s * H + h] + adp[h];
                v = (v > 0.f) ? v : 0.2f * v;
                float p = __expf(v - mh[h]);
                lh[h] += p;
                p_wave[(i - base) * H + h] = p;
            }
        }
        int cnt = min(64, hi - base);
        for (int j = 0; j < cnt; j++) {
            int s_j = __shfl(s, j);
            float pj = p_wave[j * H + h_lane];
            if constexpr (FV == 4 && FEAT_FP8) {
                unsigned int raw = *reinterpret_cast<const unsigned int*>(
                    ffeat + (size_t)s_j * (H * C) + lane * 4);
                facc4_8(acc, raw, pj);
            } else if constexpr (FV == 4) {
                float2 raw = *reinterpret_cast<const float2*>(
                    hfeat + (size_t)s_j * (H * C) + lane * 4);
                facc4_h(acc, raw, pj);
            } else {
                acc[0] += pj * __half2float(hfeat[(size_t)s_j * (H * C) + lane]);
            }
        }
    }
    #pragma unroll
    for (int off = 1; off < 64; off <<= 1)
        #pragma unroll
        for (int h = 0; h < H; h++)
            lh[h] += __shfl_xor(lh[h], off);

    float lsel = lh[0];
    #pragma unroll
    for (int h = 1; h < H; h++) if (h_lane == h) lsel = lh[h];
    const float inv = 1.0f / (lsel + 1e-16f);

    if constexpr (FV == 4) {
        float vx = acc[0] * inv, vy = acc[1] * inv,
              vz = acc[2] * inv, vw = acc[3] * inv;
        vx += __shfl_xor(vx, 16); vy += __shfl_xor(vy, 16);
        vz += __shfl_xor(vz, 16); vw += __shfl_xor(vw, 16);
        vx += __shfl_xor(vx, 32); vy += __shfl_xor(vy, 32);
        vz += __shfl_xor(vz, 32); vw += __shfl_xor(vw, 32);
        if (lane < 16) {
            float4 bv = *reinterpret_cast<const float4*>(&bias[lane * 4]);
            float ox = fmaxf(0.25f * vx + bv.x, 0.f);
            float oy = fmaxf(0.25f * vy + bv.y, 0.f);
            float oz = fmaxf(0.25f * vz + bv.z, 0.f);
            float ow = fmaxf(0.25f * vw + bv.w, 0.f);
            if constexpr (OUT_HALF) {
                half4v hv = { (_Float16)ox, (_Float16)oy, (_Float16)oz, (_Float16)ow };
                *reinterpret_cast<half4v*>((_Float16*)out_v + (size_t)d * C + lane * 4) = hv;
            } else {
                float4 o = make_float4(ox, oy, oz, ow);
                *reinterpret_cast<float4*>((float*)out_v + (size_t)d * C + lane * 4) = o;
            }
        }
    } else {
        float v = acc[0] * inv;
        v += __shfl_xor(v, 32);
        if (lane < 32) {
            float o = fmaxf(0.5f * v + bias[lane], 0.f);
            if constexpr (OUT_HALF)
                ((_Float16*)out_v)[(size_t)d * C + lane] = (_Float16)o;
            else
                ((float*)out_v)[(size_t)d * C + lane] = o;
        }
    }
}

// ---------------------------------------------------------------------------
// Layer-1 aggregation v2: 4 nodes/wave, 16 lanes/node, uint4 gathers.
// Lane l16: head = l16>>2, byte offset = l16*16 (channels (l16&3)*16..+15).
// 16 nodes per block (4 waves). deg<=32 fast path, no max-sub softmax.
// ---------------------------------------------------------------------------
__global__ __launch_bounds__(256) void gat1_v2(
        const int* __restrict__ degv, const int* __restrict__ col_ell,
        const unsigned char* __restrict__ ffeat,
        const float* __restrict__ a_s, const float* __restrict__ a_d,
        const float* __restrict__ bias, _Float16* __restrict__ out, int N)
{
    const int wid  = threadIdx.x >> 6;
    const int lane = threadIdx.x & 63;
    const int nq   = lane >> 4;          // node-in-wave 0..3
    const int l16  = lane & 15;

    __shared__ float p_sh[16][128];      // [node-in-block][edge*4+head] 8KB

    const int nodeIdx = wid * 4 + nq;
    const int d  = blockIdx.x * 16 + nodeIdx;
    const bool nodeok = (d < N);
    const int lo = d * 64;

    int degc = 0;
    if (nodeok) degc = min(degv[d << 4], 64);
    const int d0 = __shfl(degc, 0), d1 = __shfl(degc, 16);
    const int d2 = __shfl(degc, 32), d3 = __shfl(degc, 48);
    const bool fast = (max(max(d0, d1), max(d2, d3)) <= 32);

    if (fast) {
        float adp[4];
        if (nodeok) {
            float4 ad4 = *reinterpret_cast<const float4*>(&a_d[d * 4]);
            adp[0] = ad4.x; adp[1] = ad4.y; adp[2] = ad4.z; adp[3] = ad4.w;
        } else {
            adp[0] = adp[1] = adp[2] = adp[3] = 0.f;
        }

        // ---- scores: 2 edges per lane (l16 and 16+l16) ----
        int s0 = 0, s1 = 0;
        float lh[4] = {0.f, 0.f, 0.f, 0.f};
        if (nodeok && l16 < degc) {
            s0 = col_ell[lo + l16];
            float4 av = *reinterpret_cast<const float4*>(&a_s[s0 * 4]);
            float ev[4] = {av.x + adp[0], av.y + adp[1],
                           av.z + adp[2], av.w + adp[3]};
            float4 pv;
            #pragma unroll
            for (int h = 0; h < 4; h++) {
                float e = (ev[h] > 0.f) ? ev[h] : 0.2f * ev[h];
                float p = __expf(e);
                lh[h] += p;
                ((float*)&pv)[h] = p;
            }
            *reinterpret_cast<float4*>(&p_sh[nodeIdx][l16 * 4]) = pv;
        }
        if (nodeok && 16 + l16 < degc) {
            s1 = col_ell[lo + 16 + l16];
            float4 av = *reinterpret_cast<const float4*>(&a_s[s1 * 4]);
            float ev[4] = {av.x + adp[0], av.y + adp[1],
                           av.z + adp[2], av.w + adp[3]};
            float4 pv;
            #pragma unroll
            for (int h = 0; h < 4; h++) {
                float e = (ev[h] > 0.f) ? ev[h] : 0.2f * ev[h];
                float p = __expf(e);
                lh[h] += p;
                ((float*)&pv)[h] = p;
            }
            *reinterpret_cast<float4*>(&p_sh[nodeIdx][(16 + l16) * 4]) = pv;
        }
        #pragma unroll
        for (int off = 1; off < 16; off <<= 1)
            #pragma unroll
            for (int h = 0; h < 4; h++)
                lh[h] += __shfl_xor(lh[h], off);

        // ---- gather: 16 lanes x uint4 (16B) per edge, 8 in flight ----
        const int sb   = nq * 16;
        const int hsel = l16 >> 2;
        const int coff = l16 * 16;
        float a0[16] = {}, a1[16] = {};
        int j = 0;
        for (; j + 8 <= degc; j += 8) {
            uint4 raw[8]; float pw[8];
            #pragma unroll
            for (int u = 0; u < 8; u++) {
                int je = j + u;
                int sj = (je < 16) ? __shfl(s0, sb + je)
                                   : __shfl(s1, sb + je - 16);
                pw[u]  = p_sh[nodeIdx][je * 4 + hsel];
                raw[u] = *reinterpret_cast<const uint4*>(
                    ffeat + (size_t)sj * 256 + coff);
            }
            #pragma unroll
            for (int u = 0; u < 8; u++)
                facc16_8((u & 1) ? a1 : a0, raw[u], pw[u]);
        }
        for (; j < degc; j++) {
            int sj = (j < 16) ? __shfl(s0, sb + j)
                              : __shfl(s1, sb + j - 16);
            float pw = p_sh[nodeIdx][j * 4 + hsel];
            uint4 raw = *reinterpret_cast<const uint4*>(
                ffeat + (size_t)sj * 256 + coff);
            facc16_8(a0, raw, pw);
        }
        #pragma unroll
        for (int k = 0; k < 16; k++) a0[k] += a1[k];

        // ---- normalize + head-mean (xor 4, 8 within 16-lane group) ----
        float lsel = lh[0];
        if (hsel == 1) lsel = lh[1];
        if (hsel == 2) lsel = lh[2];
        if (hsel == 3) lsel = lh[3];
        float inv = 1.0f / (lsel + 1e-16f);
        #pragma unroll
        for (int k = 0; k < 16; k++) {
            float v = a0[k] * inv;
            v += __shfl_xor(v, 4);
            v += __shfl_xor(v, 8);
            a0[k] = v;
        }
        if (nodeok && l16 < 4) {
            half8 hv0, hv1;
            #pragma unroll
            for (int k = 0; k < 8; k++) {
                hv0[k] = (_Float16)fmaxf(0.25f * a0[k]     + bias[l16 * 16 + k],     0.f);
                hv1[k] = (_Float16)fmaxf(0.25f * a0[8 + k] + bias[l16 * 16 + 8 + k], 0.f);
            }
            _Float16* op = out + (size_t)d * 64 + l16 * 16;
            *reinterpret_cast<half8*>(op)     = hv0;
            *reinterpret_cast<half8*>(op + 8) = hv1;
        }
        return;
    }

    // ---- rare: full-wave general path, 4 nodes sequentially ----
    const int dA = blockIdx.x * 16 + wid * 4;
    const int dg[4] = {d0, d1, d2, d3};
    for (int t = 0; t < 4; t++)
        gat_general<4, 64, true, true>(
            dA + t, (dA + t) * 64, dg[t], col_ell,
            ffeat, a_s, a_d, bias, out, N, &p_sh[wid * 4][0]);
}

// ---------------------------------------------------------------------------
// Layer-2 GAT aggregation (R17 form, 2 nodes/wave). degv = padded deg16.
// ---------------------------------------------------------------------------
template<int H, int C, bool OUT_HALF, bool FEAT_FP8>
__global__ __launch_bounds__(256) void gat_dst(
        const int* __restrict__ degv, const int* __restrict__ col_ell,
        const void* __restrict__ hfeat_v, const float* __restrict__ a_s,
        const float* __restrict__ a_d, const float* __restrict__ bias,
        void* __restrict__ out_v, int N)
{
    const int wid  = threadIdx.x >> 6;
    const int lane = threadIdx.x & 63;
    const int nw   = lane >> 5;
    const int l32  = lane & 31;

    __shared__ float p_sh[4][64 * H];

    const int d  = blockIdx.x * 8 + wid * 2 + nw;
    const bool nodeok = (d < N);
    const int lo = d * 64;

    int degc = 0;
    if (nodeok) degc = min(degv[d << 4], 64);
    const int degA = __shfl(degc, 0);
    const int degB = __shfl(degc, 32);
    const bool fast = (degA <= 32) && (degB <= 32);

    if (fast) {
        const __half* hfeat = (const __half*)hfeat_v;

        float adp[H];
        #pragma unroll
        for (int h = 0; h < H; h++) adp[h] = nodeok ? a_d[d * H + h] : 0.f;

        int s = 0;
        float lh[H];
        #pragma unroll
        for (int h = 0; h < H; h++) lh[h] = 0.f;
        const bool valid = nodeok && (l32 < degc);
        if (valid) {
            s = col_ell[lo + l32];
            float2 av = *reinterpret_cast<const float2*>(&a_s[s * 2]);
            float ev[2] = {av.x + adp[0], av.y + adp[1]};
            #pragma unroll
            for (int h = 0; h < 2; h++) {
                float e = (ev[h] > 0.f) ? ev[h] : 0.2f * ev[h];
                float p = __expf(e);
                lh[h] = p;
                p_sh[wid][nw * 32 * H + l32 * H + h] = p;
            }
        }
        #pragma unroll
        for (int off = 1; off < 32; off <<= 1)
            #pragma unroll
            for (int h = 0; h < H; h++)
                lh[h] += __shfl_xor(lh[h], off);

        const int sbase = nw * 32;

        const int q   = l32 >> 4;
        const int l16 = l32 & 15;
        const int hl2 = l16 >> 3;
        float a0[4] = {}, a1[4] = {};
        int j = 0;
        for (; j + 8 <= degc; j += 8) {
            float2 raw[4]; float pw[4];
            #pragma unroll
            for (int u = 0; u < 4; u++) {
                int je = j + 2 * u + q;
                int sj = __shfl(s, sbase + je);
                pw[u]  = p_sh[wid][nw * 64 + je * 2 + hl2];
                raw[u] = *reinterpret_cast<const float2*>(
                    (const _Float16*)hfeat + (size_t)sj * 64 + l16 * 4);
            }
            #pragma unroll
            for (int u = 0; u < 4; u++)
                facc4_h((u & 1) ? a1 : a0, raw[u], pw[u]);
        }
        for (int jr = j + q; jr < degc; jr += 2) {
            int sj = __shfl(s, sbase + jr);
            float pw = p_sh[wid][nw * 64 + jr * 2 + hl2];
            float2 raw = *reinterpret_cast<const float2*>(
                (const _Float16*)hfeat + (size_t)sj * 64 + l16 * 4);
            facc4_h(a0, raw, pw);
        }
        #pragma unroll
        for (int k = 0; k < 4; k++) {
            a0[k] += a1[k];
            a0[k] += __shfl_xor(a0[k], 16);
        }
        float lsel = (hl2 == 0) ? lh[0] : lh[1];
        float inv = 1.0f / (lsel + 1e-16f);
        #pragma unroll
        for (int k = 0; k < 4; k++) {
            float v = a0[k] * inv;
            v += __shfl_xor(v, 8);
            a0[k] = v;
        }
        if (nodeok && l32 < 8) {
            float4 bb = *reinterpret_cast<const float4*>(&bias[l32 * 4]);
            float4 o;
            o.x = fmaxf(0.5f * a0[0] + bb.x, 0.f);
            o.y = fmaxf(0.5f * a0[1] + bb.y, 0.f);
            o.z = fmaxf(0.5f * a0[2] + bb.z, 0.f);
            o.w = fmaxf(0.5f * a0[3] + bb.w, 0.f);
            *reinterpret_cast<float4*>((float*)out_v + (size_t)d * 32 + l32 * 4) = o;
        }
        return;
    }

    const int dA = blockIdx.x * 8 + wid * 2;
    gat_general<H, C, OUT_HALF, FEAT_FP8>(
        dA, dA * 64, __shfl(degc, 0), col_ell,
        hfeat_v, a_s, a_d, bias, out_v, N, p_sh[wid]);
    gat_general<H, C, OUT_HALF, FEAT_FP8>(
        dA + 1, (dA + 1) * 64, __shfl(degc, 32), col_ell,
        hfeat_v, a_s, a_d, bias, out_v, N, p_sh[wid]);
}

// ---------------------------------------------------------------------------
// Merged pool + heads (R17 form).
// ---------------------------------------------------------------------------
__global__ __launch_bounds__(256) void pool_heads(
        const float* __restrict__ h2, const int* __restrict__ batch,
        const float* __restrict__ cW1, const float* __restrict__ cb1,
        const float* __restrict__ cW2, const float* __restrict__ cb2,
        const float* __restrict__ hW1, const float* __restrict__ hb1,
        const float* __restrict__ hW2, const float* __restrict__ hb2,
        float* __restrict__ out, int N)
{
    const int g = blockIdx.x;
    const int c = threadIdx.x & 31;
    const int r = threadIdx.x >> 5;

    __shared__ int bounds[2];
    __shared__ float red[8][32];
    __shared__ float emb_s[32];
    __shared__ float hidden[32];

    if (threadIdx.x < 2) {
        int target = g + (int)threadIdx.x;
        int lo = 0, hi = N;
        while (lo < hi) {
            int mid = (lo + hi) >> 1;
            if (batch[mid] < target) lo = mid + 1; else hi = mid;
        }
        bounds[threadIdx.x] = lo;
    }
    __syncthreads();
    const int lo = bounds[0], hi = bounds[1];

    float acc = 0.f;
    for (int n = lo + r; n < hi; n += 8)
        acc += h2[(size_t)n * 32 + c];
    red[r][c] = acc;
    __syncthreads();
    if (r == 0) {
        float s = 0.f;
        #pragma unroll
        for (int i = 0; i < 8; i++) s += red[i][c];
        emb_s[c] = s / fmaxf((float)(hi - lo), 1.0f);
    }
    __syncthreads();

    if (threadIdx.x < 32) {
        int j = threadIdx.x & 15;
        bool is_halt = threadIdx.x >= 16;
        const float* w1v = is_halt ? hW1 : cW1;
        const float* b1v = is_halt ? hb1 : cb1;
        const float* w2v = is_halt ? hW2 : cW2;
        float s = b1v[j];
        #pragma unroll
        for (int cc = 0; cc < 32; cc++) s += emb_s[cc] * w1v[cc * 16 + j];
        hidden[threadIdx.x] = fmaxf(s, 0.f) * w2v[j];
    }
    __syncthreads();
    if (threadIdx.x == 0) {
        float sc = cb2[0], sh = hb2[0];
        #pragma unroll
        for (int i = 0; i < 16; i++) { sc += hidden[i]; sh += hidden[16 + i]; }
        out[g]            = 1.0f / (1.0f + __expf(-sh));   // halt
        out[G_GRAPHS + g] = 1.0f / (1.0f + __expf(-sc));   // cont
    }
}

// ---------------------------------------------------------------------------
extern "C" void kernel_launch(void* const* d_in, const int* in_sizes, int n_in,
                              void* d_out, int out_size, void* d_ws, size_t ws_size,
                              hipStream_t stream)
{
    const float* x   = (const float*)d_in[0];
    const int*   ei  = (const int*)  d_in[1];
    const int*   bat = (const int*)  d_in[2];
    const float* W1  = (const float*)d_in[3];
    const float* as1 = (const float*)d_in[4];
    const float* ad1 = (const float*)d_in[5];
    const float* b1  = (const float*)d_in[6];
    const float* W2  = (const float*)d_in[7];
    const float* as2 = (const float*)d_in[8];
    const float* ad2 = (const float*)d_in[9];
    const float* b2  = (const float*)d_in[10];
    const float* cW1 = (const float*)d_in[11];
    const float* cb1 = (const float*)d_in[12];
    const float* cW2 = (const float*)d_in[13];
    const float* cb2 = (const float*)d_in[14];
    const float* hW1 = (const float*)d_in[15];
    const float* hb1 = (const float*)d_in[16];
    const float* hW2 = (const float*)d_in[17];
    const float* hb2 = (const float*)d_in[18];

    const int N    = in_sizes[2];           // 20000
    const int E0   = in_sizes[1] / 2;       // 320000
    const int Etot = E0 + N;                // + self loops

    // ---- workspace carve (float-granular) ----
    float* w = (float*)d_ws;
    size_t o = 0;
    unsigned char* h1pre_f8 = (unsigned char*)(w + o); o += (size_t)N * 64; // [N,256] fp8
    _Float16* h1_h    = (_Float16*)(w + o); o += (size_t)N * 32;       // [N,64]
    _Float16* h2pre_h = (_Float16*)(w + o); o += (size_t)N * 32;       // [N,64]
    float* a_s1  = w + o; o += (size_t)N * 4;
    float* a_d1  = w + o; o += (size_t)N * 4;
    float* a_s2  = w + o; o += (size_t)N * 2;
    float* a_d2  = w + o; o += (size_t)N * 2;
    float* h2    = w + o; o += (size_t)N * 32;
    int* deg16   = (int*)(w + o); o += (size_t)N * 16;   // 1 counter / 64B line
    int* col_ell = (int*)(w + o); o += (size_t)N * 64;   // ELL, stride 64
    (void)ws_size; (void)n_in; (void)out_size;

    const dim3 blk(256);
    const int eb   = (Etot + 255) / 256;
    const int nb8  = (N + 7) / 8;
    const int nb16 = (N + 15) / 16;
    const int mb   = (N + 63) / 64;

    // ---- zero padded deg ----
    const int n4 = N * 4;
    zero_deg<<<(n4 + 255) / 256, blk, 0, stream>>>((int4*)deg16, n4);

    // ---- FUSED: layer-1 GEMM (blocks [0,mb)) + ELL build (rest) ----
    ell_gemm1<<<mb + eb, blk, 0, stream>>>(
        ei, deg16, col_ell, E0, Etot, mb,
        x, W1, h1pre_f8, as1, ad1, a_s1, a_d1, N);

    // ---- layer 1 aggregation v2 (4 nodes/wave, uint4 gathers) ----
    gat1_v2<<<nb16, blk, 0, stream>>>(
        deg16, col_ell, h1pre_f8, a_s1, a_d1, b1, h1_h, N);

    // ---- layer 2: GEMM + aggregation ----
    gemm2_kernel<<<mb, blk, 0, stream>>>(
        h1_h, W2, h2pre_h, as2, ad2, a_s2, a_d2, N);
    gat_dst<2, 32, false, false><<<nb8, blk, 0, stream>>>(
        deg16, col_ell, h2pre_h, a_s2, a_d2, b2, h2, N);

    // ---- pool + heads ----
    pool_heads<<<G_GRAPHS, blk, 0, stream>>>(
        h2, bat, cW1, cb1, cW2, cb2, hW1, hb1, hW2, hb2, (float*)d_out, N);
}

// Round 10
// 105.549 us; speedup vs baseline: 1.1502x; 1.1502x over previous
//
#include <hip/hip_runtime.h>
#include <hip/hip_fp16.h>

// ---------------------------------------------------------------------------
// GAT policy module: 2x GAT layer (head-mean) + mean-pool + 2 MLP heads.
// Round 25: REVERT gat1 to R17 form (R24's 4-node/wave uint4 variant was
// 46us vs 37; occupancy 13%, more latency-exposed). ELL attacked on the
// measured mechanism: atomic-CONCURRENCY (R23 refuted line contention).
//  (a) ELL: 4 edges/thread (2x int4 index loads, 4 independent atomicAdds
//      in flight, 4 stores). 313 ELL blocks + 313 GEMM blocks = 626 total
//      -> whole fused kernel resident in one generation.
//  (b) self-loops OFF the atomic path: init kernel pre-reserves slot 0
//      (deg16[n*16]=1, col_ell[n*64]=n) with coalesced int4 stores.
//  (c) ell_gemm1 fusion + gemm1_v2 (A staged once) kept from R23.
// Budget (measured): fused 41 (ELL~28 + gemm1 overlap) | gat1 ~25-37 |
// gat2 ~21-26 | gemm2 3 | pool 1.5 | zero 1.
// MFMA fragment layouts (HW-verified): A[m=lane&15][k=quad*8+j],
// B[k=quad*8+j][n=lane&15], C/D col=lane&15, row=quad*4+reg.
// ---------------------------------------------------------------------------

#define G_GRAPHS 64

using half8   = __attribute__((ext_vector_type(8))) _Float16;
using half4v  = __attribute__((ext_vector_type(4))) _Float16;
using floatx4 = __attribute__((ext_vector_type(4))) float;
using floatx2 = __attribute__((ext_vector_type(2))) float;

// ---------------------------------------------------------------------------
// Init: deg16 line counters = 1 (self-loop pre-reserved at slot 0) and
// col_ell[n*64] = n. Coalesced int4 stores for deg16.
// ---------------------------------------------------------------------------
__global__ __launch_bounds__(256) void init_deg_ell(
        int4* __restrict__ deg4, int* __restrict__ col_ell, int N)
{
    int i = blockIdx.x * 256 + threadIdx.x;     // int4 index over deg16
    int n4 = N * 4;
    if (i < n4) {
        deg4[i] = ((i & 3) == 0) ? int4{1, 0, 0, 0} : int4{0, 0, 0, 0};
        if ((i & 3) == 0) {
            int n = i >> 2;
            col_ell[(size_t)n * 64] = n;        // self-loop at slot 0
        }
    }
}

// ---------------------------------------------------------------------------
// FUSED: layer-1 GEMM v2 (blocks [0,mb)) + ELL build (blocks [mb,mb+eb4)).
// ELL: 4 edges per thread, independent atomics in flight.
// ---------------------------------------------------------------------------
__global__ __launch_bounds__(256) void ell_gemm1(
        const int* __restrict__ ei, int* __restrict__ deg16,
        int* __restrict__ col_ell, int E0, int mb,
        const float* __restrict__ A, const float* __restrict__ B,
        unsigned char* __restrict__ C8, const float* __restrict__ att_s,
        const float* __restrict__ att_d, float* __restrict__ a_s,
        float* __restrict__ a_d, int M)
{
    __shared__ _Float16 As[64][136];
    __shared__ _Float16 Bt[64][136];

    if ((int)blockIdx.x >= mb) {
        // ---- ELL build: 4 consecutive edges per thread ----
        int idx4 = ((int)blockIdx.x - mb) * 1024 + threadIdx.x * 4;
        if (idx4 + 3 < E0) {
            int4 s4 = *reinterpret_cast<const int4*>(&ei[idx4]);
            int4 d4 = *reinterpret_cast<const int4*>(&ei[E0 + idx4]);
            int sl0 = atomicAdd(&deg16[d4.x << 4], 1);
            int sl1 = atomicAdd(&deg16[d4.y << 4], 1);
            int sl2 = atomicAdd(&deg16[d4.z << 4], 1);
            int sl3 = atomicAdd(&deg16[d4.w << 4], 1);
            if (sl0 < 64) col_ell[(size_t)d4.x * 64 + sl0] = s4.x;
            if (sl1 < 64) col_ell[(size_t)d4.y * 64 + sl1] = s4.y;
            if (sl2 < 64) col_ell[(size_t)d4.z * 64 + sl2] = s4.z;
            if (sl3 < 64) col_ell[(size_t)d4.w * 64 + sl3] = s4.w;
        } else {
            for (int j = 0; j < 4; j++) {
                int idx = idx4 + j;
                if (idx < E0) {
                    int src = ei[idx];
                    int dst = ei[E0 + idx];
                    int slot = atomicAdd(&deg16[dst << 4], 1);
                    if (slot < 64)
                        col_ell[(size_t)dst * 64 + slot] = src;
                }
            }
        }
        return;
    }

    // ---- gemm1_v2: A-tile staged once, by-loop over 4 column blocks ----
    const int tid  = threadIdx.x;
    const int row0 = blockIdx.x * 64;
    const int wid  = tid >> 6;
    const int lane = tid & 63;
    const int r    = lane & 15;
    const int quad = lane >> 4;
    const int rw0  = wid * 16;

    const int arow = tid >> 2;
    const int akc  = (tid & 3) * 32;
    const int agr  = row0 + arow;

    #pragma unroll
    for (int i = 0; i < 4; i++) {
        half8 v = {};
        if (agr < M) {
            const float* p = &A[(size_t)agr * 128 + akc + i * 8];
            float4 f0 = *reinterpret_cast<const float4*>(p);
            float4 f1 = *reinterpret_cast<const float4*>(p + 4);
            v[0] = (_Float16)f0.x; v[1] = (_Float16)f0.y;
            v[2] = (_Float16)f0.z; v[3] = (_Float16)f0.w;
            v[4] = (_Float16)f1.x; v[5] = (_Float16)f1.y;
            v[6] = (_Float16)f1.z; v[7] = (_Float16)f1.w;
        }
        *reinterpret_cast<half8*>(&As[arow][akc + i * 8]) = v;
    }

    for (int by = 0; by < 4; by++) {
        __syncthreads();

        #pragma unroll
        for (int i = 0; i < 8; i++) {
            int id = tid + 256 * i;
            int k  = id >> 4;
            int n4 = (id & 15) * 4;
            float4 f = *reinterpret_cast<const float4*>(
                &B[(size_t)k * 256 + by * 64 + n4]);
            Bt[n4 + 0][k] = (_Float16)f.x;
            Bt[n4 + 1][k] = (_Float16)f.y;
            Bt[n4 + 2][k] = (_Float16)f.z;
            Bt[n4 + 3][k] = (_Float16)f.w;
        }
        __syncthreads();

        floatx4 acc[4] = {};
        #pragma unroll
        for (int s = 0; s < 4; s++) {
            half8 af = *reinterpret_cast<const half8*>(&As[rw0 + r][s * 32 + quad * 8]);
            #pragma unroll
            for (int nt = 0; nt < 4; nt++) {
                half8 bf = *reinterpret_cast<const half8*>(&Bt[nt * 16 + r][s * 32 + quad * 8]);
                acc[nt] = __builtin_amdgcn_mfma_f32_16x16x32_f16(af, bf, acc[nt], 0, 0, 0);
            }
        }

        float ps[4], pd[4];
        #pragma unroll
        for (int reg = 0; reg < 4; reg++) { ps[reg] = 0.f; pd[reg] = 0.f; }
        #pragma unroll
        for (int nt = 0; nt < 4; nt++) {
            int cl = nt * 16 + r;
            float ws = att_s[by * 64 + cl];
            float wd = att_d[by * 64 + cl];
            #pragma unroll
            for (int reg = 0; reg < 4; reg++) {
                ps[reg] += acc[nt][reg] * ws;
                pd[reg] += acc[nt][reg] * wd;
            }
        }
        #pragma unroll
        for (int off = 1; off < 16; off <<= 1)
            #pragma unroll
            for (int reg = 0; reg < 4; reg++) {
                ps[reg] += __shfl_xor(ps[reg], off);
                pd[reg] += __shfl_xor(pd[reg], off);
            }
        if (r == 0) {
            #pragma unroll
            for (int reg = 0; reg < 4; reg++) {
                int gr = row0 + rw0 + quad * 4 + reg;
                if (gr < M) {
                    a_s[gr * 4 + by] = ps[reg];
                    a_d[gr * 4 + by] = pd[reg];
                }
            }
        }

        __syncthreads();
        unsigned char (*lds8)[80] = reinterpret_cast<unsigned char(*)[80]>(&Bt[0][0]);
        #pragma unroll
        for (int nt = 0; nt < 4; nt++) {
            #pragma unroll
            for (int reg = 0; reg < 4; reg++) {
                int wv = __builtin_amdgcn_cvt_pk_fp8_f32(
                    acc[nt][reg], acc[nt][reg], 0, false);
                lds8[rw0 + quad * 4 + reg][nt * 16 + r] = (unsigned char)(wv & 0xFF);
            }
        }
        __syncthreads();
        {
            int row = tid >> 2;
            int c16 = (tid & 3) * 16;
            int gr  = row0 + row;
            if (gr < M) {
                int4 v = *reinterpret_cast<const int4*>(&lds8[row][c16]);
                *reinterpret_cast<int4*>(&C8[(size_t)gr * 256 + by * 64 + c16]) = v;
            }
        }
    }
}

// ---------------------------------------------------------------------------
// GEMM tile body (device fn) - used by gemm2 only (K=64, fp16 A, fp32 B).
// ---------------------------------------------------------------------------
template<int K, int HPB, bool A_FP32, bool B_FP32>
__device__ __forceinline__ void gemm_att_tile(
        const void* __restrict__ A_v, const void* __restrict__ B_v,
        void* __restrict__ C_out, const float* __restrict__ att_s,
        const float* __restrict__ att_d, float* __restrict__ a_s,
        float* __restrict__ a_d, int M, int Ntot, int Htot,
        int row0, int col0, int by,
        _Float16 (*As)[K + 8], _Float16 (*Bt)[K + 8])
{
    constexpr int CPH = 64 / HPB;
    constexpr int NTH = 4 / HPB;
    const int tid = threadIdx.x;

    {
        int row = tid >> 2;
        int kc  = (tid & 3) * (K / 4);
        int gr  = row0 + row;
        #pragma unroll
        for (int i = 0; i < K / 32; i++) {
            half8 v = {};
            if (gr < M) {
                if constexpr (A_FP32) {
                    const float* Af = (const float*)A_v;
                    float4 f0 = *reinterpret_cast<const float4*>(&Af[(size_t)gr * K + kc + i * 8]);
                    float4 f1 = *reinterpret_cast<const float4*>(&Af[(size_t)gr * K + kc + i * 8 + 4]);
                    v[0] = (_Float16)f0.x; v[1] = (_Float16)f0.y;
                    v[2] = (_Float16)f0.z; v[3] = (_Float16)f0.w;
                    v[4] = (_Float16)f1.x; v[5] = (_Float16)f1.y;
                    v[6] = (_Float16)f1.z; v[7] = (_Float16)f1.w;
                } else {
                    const _Float16* Ah = (const _Float16*)A_v;
                    v = *reinterpret_cast<const half8*>(&Ah[(size_t)gr * K + kc + i * 8]);
                }
            }
            *reinterpret_cast<half8*>(&As[row][kc + i * 8]) = v;
        }
    }
    {
        #pragma unroll
        for (int i = 0; i < K / 16; i++) {
            int id = tid + 256 * i;
            int k  = id >> 4;
            int n4 = (id & 15) * 4;
            _Float16 b0, b1, b2, b3;
            if constexpr (B_FP32) {
                const float* Bf = (const float*)B_v;
                float4 f = *reinterpret_cast<const float4*>(&Bf[(size_t)k * Ntot + col0 + n4]);
                b0 = (_Float16)f.x; b1 = (_Float16)f.y;
                b2 = (_Float16)f.z; b3 = (_Float16)f.w;
            } else {
                const _Float16* Bh = (const _Float16*)B_v;
                half4v v = *reinterpret_cast<const half4v*>(&Bh[(size_t)k * Ntot + col0 + n4]);
                b0 = v[0]; b1 = v[1]; b2 = v[2]; b3 = v[3];
            }
            Bt[n4 + 0][k] = b0; Bt[n4 + 1][k] = b1;
            Bt[n4 + 2][k] = b2; Bt[n4 + 3][k] = b3;
        }
    }
    __syncthreads();

    const int wid  = tid >> 6;
    const int lane = tid & 63;
    const int r    = lane & 15;
    const int quad = lane >> 4;
    const int rw0  = wid * 16;

    floatx4 acc[4] = {};
    #pragma unroll
    for (int s = 0; s < K / 32; s++) {
        half8 af = *reinterpret_cast<const half8*>(&As[rw0 + r][s * 32 + quad * 8]);
        #pragma unroll
        for (int nt = 0; nt < 4; nt++) {
            half8 bf = *reinterpret_cast<const half8*>(&Bt[nt * 16 + r][s * 32 + quad * 8]);
            acc[nt] = __builtin_amdgcn_mfma_f32_16x16x32_f16(af, bf, acc[nt], 0, 0, 0);
        }
    }

    float ps[HPB][4], pd[HPB][4];
    #pragma unroll
    for (int hl = 0; hl < HPB; hl++)
        #pragma unroll
        for (int reg = 0; reg < 4; reg++) { ps[hl][reg] = 0.f; pd[hl][reg] = 0.f; }

    #pragma unroll
    for (int nt = 0; nt < 4; nt++) {
        int hl = nt / NTH;
        int cl = (nt % NTH) * 16 + r;
        int hglob = by * HPB + hl;
        float ws = att_s[hglob * CPH + cl];
        float wd = att_d[hglob * CPH + cl];
        #pragma unroll
        for (int reg = 0; reg < 4; reg++) {
            ps[hl][reg] += acc[nt][reg] * ws;
            pd[hl][reg] += acc[nt][reg] * wd;
        }
    }
    #pragma unroll
    for (int off = 1; off < 16; off <<= 1)
        #pragma unroll
        for (int hl = 0; hl < HPB; hl++)
            #pragma unroll
            for (int reg = 0; reg < 4; reg++) {
                ps[hl][reg] += __shfl_xor(ps[hl][reg], off);
                pd[hl][reg] += __shfl_xor(pd[hl][reg], off);
            }
    if (r == 0) {
        #pragma unroll
        for (int reg = 0; reg < 4; reg++) {
            int gr = row0 + rw0 + quad * 4 + reg;
            if (gr < M) {
                #pragma unroll
                for (int hl = 0; hl < HPB; hl++) {
                    int hglob = by * HPB + hl;
                    a_s[gr * Htot + hglob] = ps[hl][reg];
                    a_d[gr * Htot + hglob] = pd[hl][reg];
                }
            }
        }
    }

    _Float16* Ch = (_Float16*)C_out;
    #pragma unroll
    for (int nt = 0; nt < 4; nt++) {
        #pragma unroll
        for (int reg = 0; reg < 4; reg++) {
            int gr = row0 + rw0 + quad * 4 + reg;
            if (gr < M)
                Ch[(size_t)gr * Ntot + col0 + nt * 16 + r] = (_Float16)acc[nt][reg];
        }
    }
}

// ---------------------------------------------------------------------------
__global__ __launch_bounds__(256) void gemm2_kernel(
        const _Float16* __restrict__ A, const float* __restrict__ B,
        _Float16* __restrict__ Ch, const float* __restrict__ att_s,
        const float* __restrict__ att_d, float* __restrict__ a_s,
        float* __restrict__ a_d, int M)
{
    __shared__ _Float16 As[64][72];
    __shared__ _Float16 Bt[64][72];
    gemm_att_tile<64, 2, false, true>(
        A, B, Ch, att_s, att_d, a_s, a_d,
        M, 64, 2, blockIdx.x * 64, 0, 0, As, Bt);
}

// ---------------------------------------------------------------------------
// FMA helpers.
// ---------------------------------------------------------------------------
__device__ inline void facc4_h(float* a, float2 raw, float p) {
    __half2 h0 = *reinterpret_cast<__half2*>(&raw.x);
    __half2 h1 = *reinterpret_cast<__half2*>(&raw.y);
    float2 f0 = __half22float2(h0), f1 = __half22float2(h1);
    a[0] += p * f0.x; a[1] += p * f0.y; a[2] += p * f1.x; a[3] += p * f1.y;
}
__device__ inline void facc4_8(float* a, unsigned int w, float p) {
    floatx2 lo = __builtin_amdgcn_cvt_pk_f32_fp8((int)w, false);
    floatx2 hi = __builtin_amdgcn_cvt_pk_f32_fp8((int)w, true);
    a[0] += p * lo[0]; a[1] += p * lo[1]; a[2] += p * hi[0]; a[3] += p * hi[1];
}
__device__ inline void facc8_8(float* a, uint2 w, float p) {
    facc4_8(a,     w.x, p);
    facc4_8(a + 4, w.y, p);
}

// ---------------------------------------------------------------------------
// General path (32 < deg <= 64, rare): full-wave per-node, max-subtraction.
// ---------------------------------------------------------------------------
template<int H, int C, bool OUT_HALF, bool FEAT_FP8>
__device__ void gat_general(
        int d, int lo, int degc, const int* __restrict__ colidx,
        const void* __restrict__ hfeat_v, const float* __restrict__ a_s,
        const float* __restrict__ a_d, const float* __restrict__ bias,
        void* __restrict__ out_v, int N, float* p_wave)
{
    if (d >= N) return;
    constexpr int FV = (H * C) / 64;
    const int lane = threadIdx.x & 63;
    const int hi = lo + degc;
    const __half* hfeat = (const __half*)hfeat_v;
    const unsigned char* ffeat = (const unsigned char*)hfeat_v;
    const int h_lane = (lane * FV) / C;

    float adp[H];
    #pragma unroll
    for (int h = 0; h < H; h++) adp[h] = a_d[d * H + h];
    float lh[H];
    #pragma unroll
    for (int h = 0; h < H; h++) lh[h] = 0.f;
    float acc[FV];
    #pragma unroll
    for (int v = 0; v < FV; v++) acc[v] = 0.f;

    float mh[H];
    #pragma unroll
    for (int h = 0; h < H; h++) mh[h] = -3.0e38f;
    for (int i = lo + lane; i < hi; i += 64) {
        int s = colidx[i];
        #pragma unroll
        for (int h = 0; h < H; h++) {
            float v = a_s[s * H + h] + adp[h];
            v = (v > 0.f) ? v : 0.2f * v;
            mh[h] = fmaxf(mh[h], v);
        }
    }
    #pragma unroll
    for (int off = 1; off < 64; off <<= 1)
        #pragma unroll
        for (int h = 0; h < H; h++)
            mh[h] = fmaxf(mh[h], __shfl_xor(mh[h], off));

    for (int base = lo; base < hi; base += 64) {
        int i = base + lane;
        int s = 0;
        if (i < hi) {
            s = colidx[i];
            #pragma unroll
            for (int h = 0; h < H; h++) {
                float v = a_s[s * H + h] + adp[h];
                v = (v > 0.f) ? v : 0.2f * v;
                float p = __expf(v - mh[h]);
                lh[h] += p;
                p_wave[(i - base) * H + h] = p;
            }
        }
        int cnt = min(64, hi - base);
        for (int j = 0; j < cnt; j++) {
            int s_j = __shfl(s, j);
            float pj = p_wave[j * H + h_lane];
            if constexpr (FV == 4 && FEAT_FP8) {
                unsigned int raw = *reinterpret_cast<const unsigned int*>(
                    ffeat + (size_t)s_j * (H * C) + lane * 4);
                facc4_8(acc, raw, pj);
            } else if constexpr (FV == 4) {
                float2 raw = *reinterpret_cast<const float2*>(
                    hfeat + (size_t)s_j * (H * C) + lane * 4);
                facc4_h(acc, raw, pj);
            } else {
                acc[0] += pj * __half2float(hfeat[(size_t)s_j * (H * C) + lane]);
            }
        }
    }
    #pragma unroll
    for (int off = 1; off < 64; off <<= 1)
        #pragma unroll
        for (int h = 0; h < H; h++)
            lh[h] += __shfl_xor(lh[h], off);

    float lsel = lh[0];
    #pragma unroll
    for (int h = 1; h < H; h++) if (h_lane == h) lsel = lh[h];
    const float inv = 1.0f / (lsel + 1e-16f);

    if constexpr (FV == 4) {
        float vx = acc[0] * inv, vy = acc[1] * inv,
              vz = acc[2] * inv, vw = acc[3] * inv;
        vx += __shfl_xor(vx, 16); vy += __shfl_xor(vy, 16);
        vz += __shfl_xor(vz, 16); vw += __shfl_xor(vw, 16);
        vx += __shfl_xor(vx, 32); vy += __shfl_xor(vy, 32);
        vz += __shfl_xor(vz, 32); vw += __shfl_xor(vw, 32);
        if (lane < 16) {
            float4 bv = *reinterpret_cast<const float4*>(&bias[lane * 4]);
            float ox = fmaxf(0.25f * vx + bv.x, 0.f);
            float oy = fmaxf(0.25f * vy + bv.y, 0.f);
            float oz = fmaxf(0.25f * vz + bv.z, 0.f);
            float ow = fmaxf(0.25f * vw + bv.w, 0.f);
            if constexpr (OUT_HALF) {
                half4v hv = { (_Float16)ox, (_Float16)oy, (_Float16)oz, (_Float16)ow };
                *reinterpret_cast<half4v*>((_Float16*)out_v + (size_t)d * C + lane * 4) = hv;
            } else {
                float4 o = make_float4(ox, oy, oz, ow);
                *reinterpret_cast<float4*>((float*)out_v + (size_t)d * C + lane * 4) = o;
            }
        }
    } else {
        float v = acc[0] * inv;
        v += __shfl_xor(v, 32);
        if (lane < 32) {
            float o = fmaxf(0.5f * v + bias[lane], 0.f);
            if constexpr (OUT_HALF)
                ((_Float16*)out_v)[(size_t)d * C + lane] = (_Float16)o;
            else
                ((float*)out_v)[(size_t)d * C + lane] = o;
        }
    }
}

// ---------------------------------------------------------------------------
// Fused GAT aggregation over ELL rows, 2 nodes per wave (R17 form).
// degv is the PADDED deg16 array (stride 16 ints).
// ---------------------------------------------------------------------------
template<int H, int C, bool OUT_HALF, bool FEAT_FP8>
__global__ __launch_bounds__(256) void gat_dst(
        const int* __restrict__ degv, const int* __restrict__ col_ell,
        const void* __restrict__ hfeat_v, const float* __restrict__ a_s,
        const float* __restrict__ a_d, const float* __restrict__ bias,
        void* __restrict__ out_v, int N)
{
    const int wid  = threadIdx.x >> 6;
    const int lane = threadIdx.x & 63;
    const int nw   = lane >> 5;          // node-in-wave (0/1)
    const int l32  = lane & 31;

    __shared__ float p_sh[4][64 * H];    // per wave: 2 nodes x 32 edges x H

    const int d  = blockIdx.x * 8 + wid * 2 + nw;
    const bool nodeok = (d < N);
    const int lo = d * 64;               // ELL row base

    int degc = 0;
    if (nodeok) degc = min(degv[d << 4], 64);
    const int degA = __shfl(degc, 0);
    const int degB = __shfl(degc, 32);
    const bool fast = (degA <= 32) && (degB <= 32);

    if (fast) {
        const __half* hfeat = (const __half*)hfeat_v;
        const unsigned char* ffeat = (const unsigned char*)hfeat_v;

        float adp[H];
        #pragma unroll
        for (int h = 0; h < H; h++) adp[h] = nodeok ? a_d[d * H + h] : 0.f;

        // ---- phase A: scores -> p = exp(e) directly (no max-sub) ----
        int s = 0;
        float lh[H];
        #pragma unroll
        for (int h = 0; h < H; h++) lh[h] = 0.f;
        const bool valid = nodeok && (l32 < degc);
        if (valid) {
            s = col_ell[lo + l32];
            if constexpr (H == 4) {
                float4 av = *reinterpret_cast<const float4*>(&a_s[s * 4]);
                float ev[4] = {av.x + adp[0], av.y + adp[1],
                               av.z + adp[2], av.w + adp[3]};
                #pragma unroll
                for (int h = 0; h < 4; h++) {
                    float e = (ev[h] > 0.f) ? ev[h] : 0.2f * ev[h];
                    float p = __expf(e);
                    lh[h] = p;
                    p_sh[wid][nw * 32 * H + l32 * H + h] = p;
                }
            } else {
                float2 av = *reinterpret_cast<const float2*>(&a_s[s * 2]);
                float ev[2] = {av.x + adp[0], av.y + adp[1]};
                #pragma unroll
                for (int h = 0; h < 2; h++) {
                    float e = (ev[h] > 0.f) ? ev[h] : 0.2f * ev[h];
                    float p = __expf(e);
                    lh[h] = p;
                    p_sh[wid][nw * 32 * H + l32 * H + h] = p;
                }
            }
        }
        #pragma unroll
        for (int off = 1; off < 32; off <<= 1)
            #pragma unroll
            for (int h = 0; h < H; h++)
                lh[h] += __shfl_xor(lh[h], off);

        const int sbase = nw * 32;

        if constexpr (H == 4) {
            // ---- L1: 32 lanes x 8B fp8 = full row per edge ----
            const int hl = l32 >> 3;
            float a0[8] = {}, a1[8] = {};
            int j = 0;
            for (; j + 8 <= degc; j += 8) {
                uint2 raw[8]; float pw[8];
                #pragma unroll
                for (int u = 0; u < 8; u++) {
                    int sj = __shfl(s, sbase + j + u);
                    pw[u]  = p_sh[wid][nw * 128 + (j + u) * 4 + hl];
                    raw[u] = *reinterpret_cast<const uint2*>(
                        ffeat + (size_t)sj * 256 + l32 * 8);
                }
                #pragma unroll
                for (int u = 0; u < 8; u++)
                    facc8_8((u & 1) ? a1 : a0, raw[u], pw[u]);
            }
            for (; j < degc; j++) {
                int sj = __shfl(s, sbase + j);
                float pw = p_sh[wid][nw * 128 + j * 4 + hl];
                uint2 raw = *reinterpret_cast<const uint2*>(
                    ffeat + (size_t)sj * 256 + l32 * 8);
                facc8_8(a0, raw, pw);
            }
            #pragma unroll
            for (int k = 0; k < 8; k++) a0[k] += a1[k];

            float lsel = lh[0];
            #pragma unroll
            for (int h = 1; h < 4; h++) if (hl == h) lsel = lh[h];
            float inv = 1.0f / (lsel + 1e-16f);
            #pragma unroll
            for (int k = 0; k < 8; k++) {
                float v = a0[k] * inv;
                v += __shfl_xor(v, 8);       // head-mean (within half)
                v += __shfl_xor(v, 16);
                a0[k] = v;
            }
            if (nodeok && l32 < 8) {
                float4 b0 = *reinterpret_cast<const float4*>(&bias[l32 * 8]);
                float4 b1 = *reinterpret_cast<const float4*>(&bias[l32 * 8 + 4]);
                float bb[8] = {b0.x, b0.y, b0.z, b0.w, b1.x, b1.y, b1.z, b1.w};
                half8 hv;
                #pragma unroll
                for (int k = 0; k < 8; k++)
                    hv[k] = (_Float16)fmaxf(0.25f * a0[k] + bb[k], 0.f);
                *reinterpret_cast<half8*>((_Float16*)out_v + (size_t)d * 64 + l32 * 8) = hv;
            }
        } else {
            // ---- L2: 16 lanes x 8B fp16, 2 edges concurrent per half ----
            const int q   = l32 >> 4;
            const int l16 = l32 & 15;
            const int hl2 = l16 >> 3;
            float a0[4] = {}, a1[4] = {};
            int j = 0;
            for (; j + 8 <= degc; j += 8) {
                float2 raw[4]; float pw[4];
                #pragma unroll
                for (int u = 0; u < 4; u++) {
                    int je = j + 2 * u + q;
                    int sj = __shfl(s, sbase + je);
                    pw[u]  = p_sh[wid][nw * 64 + je * 2 + hl2];
                    raw[u] = *reinterpret_cast<const float2*>(
                        (const _Float16*)hfeat + (size_t)sj * 64 + l16 * 4);
                }
                #pragma unroll
                for (int u = 0; u < 4; u++)
                    facc4_h((u & 1) ? a1 : a0, raw[u], pw[u]);
            }
            for (int jr = j + q; jr < degc; jr += 2) {
                int sj = __shfl(s, sbase + jr);
                float pw = p_sh[wid][nw * 64 + jr * 2 + hl2];
                float2 raw = *reinterpret_cast<const float2*>(
                    (const _Float16*)hfeat + (size_t)sj * 64 + l16 * 4);
                facc4_h(a0, raw, pw);
            }
            #pragma unroll
            for (int k = 0; k < 4; k++) {
                a0[k] += a1[k];
                a0[k] += __shfl_xor(a0[k], 16);   // q-combine within half
            }
            float lsel = (hl2 == 0) ? lh[0] : lh[1];
            float inv = 1.0f / (lsel + 1e-16f);
            #pragma unroll
            for (int k = 0; k < 4; k++) {
                float v = a0[k] * inv;
                v += __shfl_xor(v, 8);            // head-mean
                a0[k] = v;
            }
            if (nodeok && l32 < 8) {
                float4 bb = *reinterpret_cast<const float4*>(&bias[l32 * 4]);
                float4 o;
                o.x = fmaxf(0.5f * a0[0] + bb.x, 0.f);
                o.y = fmaxf(0.5f * a0[1] + bb.y, 0.f);
                o.z = fmaxf(0.5f * a0[2] + bb.z, 0.f);
                o.w = fmaxf(0.5f * a0[3] + bb.w, 0.f);
                *reinterpret_cast<float4*>((float*)out_v + (size_t)d * 32 + l32 * 4) = o;
            }
        }
        return;
    }

    // ---- rare: full-wave general path, each node sequentially ----
    const int dA = blockIdx.x * 8 + wid * 2;
    gat_general<H, C, OUT_HALF, FEAT_FP8>(
        dA, dA * 64, __shfl(degc, 0), col_ell,
        hfeat_v, a_s, a_d, bias, out_v, N, p_sh[wid]);
    gat_general<H, C, OUT_HALF, FEAT_FP8>(
        dA + 1, (dA + 1) * 64, __shfl(degc, 32), col_ell,
        hfeat_v, a_s, a_d, bias, out_v, N, p_sh[wid]);
}

// ---------------------------------------------------------------------------
// Merged pool + heads (R17 form).
// ---------------------------------------------------------------------------
__global__ __launch_bounds__(256) void pool_heads(
        const float* __restrict__ h2, const int* __restrict__ batch,
        const float* __restrict__ cW1, const float* __restrict__ cb1,
        const float* __restrict__ cW2, const float* __restrict__ cb2,
        const float* __restrict__ hW1, const float* __restrict__ hb1,
        const float* __restrict__ hW2, const float* __restrict__ hb2,
        float* __restrict__ out, int N)
{
    const int g = blockIdx.x;
    const int c = threadIdx.x & 31;
    const int r = threadIdx.x >> 5;

    __shared__ int bounds[2];
    __shared__ float red[8][32];
    __shared__ float emb_s[32];
    __shared__ float hidden[32];

    if (threadIdx.x < 2) {
        int target = g + (int)threadIdx.x;
        int lo = 0, hi = N;
        while (lo < hi) {
            int mid = (lo + hi) >> 1;
            if (batch[mid] < target) lo = mid + 1; else hi = mid;
        }
        bounds[threadIdx.x] = lo;
    }
    __syncthreads();
    const int lo = bounds[0], hi = bounds[1];

    float acc = 0.f;
    for (int n = lo + r; n < hi; n += 8)
        acc += h2[(size_t)n * 32 + c];
    red[r][c] = acc;
    __syncthreads();
    if (r == 0) {
        float s = 0.f;
        #pragma unroll
        for (int i = 0; i < 8; i++) s += red[i][c];
        emb_s[c] = s / fmaxf((float)(hi - lo), 1.0f);
    }
    __syncthreads();

    if (threadIdx.x < 32) {
        int j = threadIdx.x & 15;
        bool is_halt = threadIdx.x >= 16;
        const float* w1v = is_halt ? hW1 : cW1;
        const float* b1v = is_halt ? hb1 : cb1;
        const float* w2v = is_halt ? hW2 : cW2;
        float s = b1v[j];
        #pragma unroll
        for (int cc = 0; cc < 32; cc++) s += emb_s[cc] * w1v[cc * 16 + j];
        hidden[threadIdx.x] = fmaxf(s, 0.f) * w2v[j];
    }
    __syncthreads();
    if (threadIdx.x == 0) {
        float sc = cb2[0], sh = hb2[0];
        #pragma unroll
        for (int i = 0; i < 16; i++) { sc += hidden[i]; sh += hidden[16 + i]; }
        out[g]            = 1.0f / (1.0f + __expf(-sh));   // halt
        out[G_GRAPHS + g] = 1.0f / (1.0f + __expf(-sc));   // cont
    }
}

// ---------------------------------------------------------------------------
extern "C" void kernel_launch(void* const* d_in, const int* in_sizes, int n_in,
                              void* d_out, int out_size, void* d_ws, size_t ws_size,
                              hipStream_t stream)
{
    const float* x   = (const float*)d_in[0];
    const int*   ei  = (const int*)  d_in[1];
    const int*   bat = (const int*)  d_in[2];
    const float* W1  = (const float*)d_in[3];
    const float* as1 = (const float*)d_in[4];
    const float* ad1 = (const float*)d_in[5];
    const float* b1  = (const float*)d_in[6];
    const float* W2  = (const float*)d_in[7];
    const float* as2 = (const float*)d_in[8];
    const float* ad2 = (const float*)d_in[9];
    const float* b2  = (const float*)d_in[10];
    const float* cW1 = (const float*)d_in[11];
    const float* cb1 = (const float*)d_in[12];
    const float* cW2 = (const float*)d_in[13];
    const float* cb2 = (const float*)d_in[14];
    const float* hW1 = (const float*)d_in[15];
    const float* hb1 = (const float*)d_in[16];
    const float* hW2 = (const float*)d_in[17];
    const float* hb2 = (const float*)d_in[18];

    const int N    = in_sizes[2];           // 20000
    const int E0   = in_sizes[1] / 2;       // 320000

    // ---- workspace carve (float-granular) ----
    float* w = (float*)d_ws;
    size_t o = 0;
    unsigned char* h1pre_f8 = (unsigned char*)(w + o); o += (size_t)N * 64; // [N,256] fp8
    _Float16* h1_h    = (_Float16*)(w + o); o += (size_t)N * 32;       // [N,64]
    _Float16* h2pre_h = (_Float16*)(w + o); o += (size_t)N * 32;       // [N,64]
    float* a_s1  = w + o; o += (size_t)N * 4;
    float* a_d1  = w + o; o += (size_t)N * 4;
    float* a_s2  = w + o; o += (size_t)N * 2;
    float* a_d2  = w + o; o += (size_t)N * 2;
    float* h2    = w + o; o += (size_t)N * 32;
    int* deg16   = (int*)(w + o); o += (size_t)N * 16;   // 1 counter / 64B line
    int* col_ell = (int*)(w + o); o += (size_t)N * 64;   // ELL, stride 64
    (void)ws_size; (void)n_in; (void)out_size;

    const dim3 blk(256);
    const int eb4 = (E0 + 1023) / 1024;      // ELL blocks, 4 edges/thread
    const int nb8 = (N + 7) / 8;
    const int mb  = (N + 63) / 64;

    // ---- init: deg16 lines = 1 (self-loop reserved), col_ell slot0 = n ----
    const int n4 = N * 4;
    init_deg_ell<<<(n4 + 255) / 256, blk, 0, stream>>>(
        (int4*)deg16, col_ell, N);

    // ---- FUSED: layer-1 GEMM (blocks [0,mb)) + ELL build (rest) ----
    ell_gemm1<<<mb + eb4, blk, 0, stream>>>(
        ei, deg16, col_ell, E0, mb,
        x, W1, h1pre_f8, as1, ad1, a_s1, a_d1, N);

    // ---- layer 1 aggregation (fp8 gather, 2 nodes/wave) ----
    gat_dst<4, 64, true, true><<<nb8, blk, 0, stream>>>(
        deg16, col_ell, h1pre_f8, a_s1, a_d1, b1, h1_h, N);

    // ---- layer 2: GEMM + aggregation ----
    gemm2_kernel<<<mb, blk, 0, stream>>>(
        h1_h, W2, h2pre_h, as2, ad2, a_s2, a_d2, N);
    gat_dst<2, 32, false, false><<<nb8, blk, 0, stream>>>(
        deg16, col_ell, h2pre_h, a_s2, a_d2, b2, h2, N);

    // ---- pool + heads ----
    pool_heads<<<G_GRAPHS, blk, 0, stream>>>(
        h2, bat, cW1, cb1, cW2, cb2, hW1, hb1, hW2, hb2, (float*)d_out, N);
}

// Round 12
// 102.517 us; speedup vs baseline: 1.1842x; 1.0296x over previous
//
#include <hip/hip_runtime.h>
#include <hip/hip_fp16.h>

// ---------------------------------------------------------------------------
// GAT policy module: 2x GAT layer (head-mean) + mean-pool + 2 MLP heads.
// Round 27: RESUBMIT of R26 (bench infra failure: UnresponsiveContainer;
// no measurement was taken - kernel is untested, not wrong).
// R26 change: halve gat2's gathered LINES: h2pre stored fp8-e4m3 (64B/row =
// 1 cache line per edge) instead of fp16 (128B = 2 lines). Mechanism
// (inferred from R23/R25 nulls + R19 traffic): gathers/scatter are bound by
// small-random-remote-line rate over the XCD fabric (~3.5TB/s effective for
// gat1); only bytes/lines-per-row moves the needle. Same trick as the
// long-verified layer-1 fp8 table. gemm2 epilogue packs acc->fp8 via the
// same LDS-alias pattern as layer-1's verified STORE_FP8 path; gat2's lane
// layout unchanged (lane l16 covers channels l16*4..+3: uint fp8 load
// replaces float2 fp16 load). ELL (R25 4-edge/thread + self-loop-free
// init), gat1, pool untouched.
// Numerics: +~6% per-value quant one layer later, smoothed by softmax mean
// (~16 edges) + 300-node pool mean; predicted absmax 0.005-0.010.
// MFMA fragment layouts (HW-verified): A[m=lane&15][k=quad*8+j],
// B[k=quad*8+j][n=lane&15], C/D col=lane&15, row=quad*4+reg.
// ---------------------------------------------------------------------------

#define G_GRAPHS 64

using half8   = __attribute__((ext_vector_type(8))) _Float16;
using half4v  = __attribute__((ext_vector_type(4))) _Float16;
using floatx4 = __attribute__((ext_vector_type(4))) float;
using floatx2 = __attribute__((ext_vector_type(2))) float;

// ---------------------------------------------------------------------------
// Init: deg16 line counters = 1 (self-loop pre-reserved at slot 0) and
// col_ell[n*64] = n. Coalesced int4 stores for deg16.
// ---------------------------------------------------------------------------
__global__ __launch_bounds__(256) void init_deg_ell(
        int4* __restrict__ deg4, int* __restrict__ col_ell, int N)
{
    int i = blockIdx.x * 256 + threadIdx.x;     // int4 index over deg16
    int n4 = N * 4;
    if (i < n4) {
        deg4[i] = ((i & 3) == 0) ? int4{1, 0, 0, 0} : int4{0, 0, 0, 0};
        if ((i & 3) == 0) {
            int n = i >> 2;
            col_ell[(size_t)n * 64] = n;        // self-loop at slot 0
        }
    }
}

// ---------------------------------------------------------------------------
// FUSED: layer-1 GEMM v2 (blocks [0,mb)) + ELL build (blocks [mb,mb+eb4)).
// ELL: 4 edges per thread, independent atomics in flight.
// ---------------------------------------------------------------------------
__global__ __launch_bounds__(256) void ell_gemm1(
        const int* __restrict__ ei, int* __restrict__ deg16,
        int* __restrict__ col_ell, int E0, int mb,
        const float* __restrict__ A, const float* __restrict__ B,
        unsigned char* __restrict__ C8, const float* __restrict__ att_s,
        const float* __restrict__ att_d, float* __restrict__ a_s,
        float* __restrict__ a_d, int M)
{
    __shared__ _Float16 As[64][136];
    __shared__ _Float16 Bt[64][136];

    if ((int)blockIdx.x >= mb) {
        // ---- ELL build: 4 consecutive edges per thread ----
        int idx4 = ((int)blockIdx.x - mb) * 1024 + threadIdx.x * 4;
        if (idx4 + 3 < E0) {
            int4 s4 = *reinterpret_cast<const int4*>(&ei[idx4]);
            int4 d4 = *reinterpret_cast<const int4*>(&ei[E0 + idx4]);
            int sl0 = atomicAdd(&deg16[d4.x << 4], 1);
            int sl1 = atomicAdd(&deg16[d4.y << 4], 1);
            int sl2 = atomicAdd(&deg16[d4.z << 4], 1);
            int sl3 = atomicAdd(&deg16[d4.w << 4], 1);
            if (sl0 < 64) col_ell[(size_t)d4.x * 64 + sl0] = s4.x;
            if (sl1 < 64) col_ell[(size_t)d4.y * 64 + sl1] = s4.y;
            if (sl2 < 64) col_ell[(size_t)d4.z * 64 + sl2] = s4.z;
            if (sl3 < 64) col_ell[(size_t)d4.w * 64 + sl3] = s4.w;
        } else {
            for (int j = 0; j < 4; j++) {
                int idx = idx4 + j;
                if (idx < E0) {
                    int src = ei[idx];
                    int dst = ei[E0 + idx];
                    int slot = atomicAdd(&deg16[dst << 4], 1);
                    if (slot < 64)
                        col_ell[(size_t)dst * 64 + slot] = src;
                }
            }
        }
        return;
    }

    // ---- gemm1_v2: A-tile staged once, by-loop over 4 column blocks ----
    const int tid  = threadIdx.x;
    const int row0 = blockIdx.x * 64;
    const int wid  = tid >> 6;
    const int lane = tid & 63;
    const int r    = lane & 15;
    const int quad = lane >> 4;
    const int rw0  = wid * 16;

    const int arow = tid >> 2;
    const int akc  = (tid & 3) * 32;
    const int agr  = row0 + arow;

    #pragma unroll
    for (int i = 0; i < 4; i++) {
        half8 v = {};
        if (agr < M) {
            const float* p = &A[(size_t)agr * 128 + akc + i * 8];
            float4 f0 = *reinterpret_cast<const float4*>(p);
            float4 f1 = *reinterpret_cast<const float4*>(p + 4);
            v[0] = (_Float16)f0.x; v[1] = (_Float16)f0.y;
            v[2] = (_Float16)f0.z; v[3] = (_Float16)f0.w;
            v[4] = (_Float16)f1.x; v[5] = (_Float16)f1.y;
            v[6] = (_Float16)f1.z; v[7] = (_Float16)f1.w;
        }
        *reinterpret_cast<half8*>(&As[arow][akc + i * 8]) = v;
    }

    for (int by = 0; by < 4; by++) {
        __syncthreads();

        #pragma unroll
        for (int i = 0; i < 8; i++) {
            int id = tid + 256 * i;
            int k  = id >> 4;
            int n4 = (id & 15) * 4;
            float4 f = *reinterpret_cast<const float4*>(
                &B[(size_t)k * 256 + by * 64 + n4]);
            Bt[n4 + 0][k] = (_Float16)f.x;
            Bt[n4 + 1][k] = (_Float16)f.y;
            Bt[n4 + 2][k] = (_Float16)f.z;
            Bt[n4 + 3][k] = (_Float16)f.w;
        }
        __syncthreads();

        floatx4 acc[4] = {};
        #pragma unroll
        for (int s = 0; s < 4; s++) {
            half8 af = *reinterpret_cast<const half8*>(&As[rw0 + r][s * 32 + quad * 8]);
            #pragma unroll
            for (int nt = 0; nt < 4; nt++) {
                half8 bf = *reinterpret_cast<const half8*>(&Bt[nt * 16 + r][s * 32 + quad * 8]);
                acc[nt] = __builtin_amdgcn_mfma_f32_16x16x32_f16(af, bf, acc[nt], 0, 0, 0);
            }
        }

        float ps[4], pd[4];
        #pragma unroll
        for (int reg = 0; reg < 4; reg++) { ps[reg] = 0.f; pd[reg] = 0.f; }
        #pragma unroll
        for (int nt = 0; nt < 4; nt++) {
            int cl = nt * 16 + r;
            float ws = att_s[by * 64 + cl];
            float wd = att_d[by * 64 + cl];
            #pragma unroll
            for (int reg = 0; reg < 4; reg++) {
                ps[reg] += acc[nt][reg] * ws;
                pd[reg] += acc[nt][reg] * wd;
            }
        }
        #pragma unroll
        for (int off = 1; off < 16; off <<= 1)
            #pragma unroll
            for (int reg = 0; reg < 4; reg++) {
                ps[reg] += __shfl_xor(ps[reg], off);
                pd[reg] += __shfl_xor(pd[reg], off);
            }
        if (r == 0) {
            #pragma unroll
            for (int reg = 0; reg < 4; reg++) {
                int gr = row0 + rw0 + quad * 4 + reg;
                if (gr < M) {
                    a_s[gr * 4 + by] = ps[reg];
                    a_d[gr * 4 + by] = pd[reg];
                }
            }
        }

        __syncthreads();
        unsigned char (*lds8)[80] = reinterpret_cast<unsigned char(*)[80]>(&Bt[0][0]);
        #pragma unroll
        for (int nt = 0; nt < 4; nt++) {
            #pragma unroll
            for (int reg = 0; reg < 4; reg++) {
                int wv = __builtin_amdgcn_cvt_pk_fp8_f32(
                    acc[nt][reg], acc[nt][reg], 0, false);
                lds8[rw0 + quad * 4 + reg][nt * 16 + r] = (unsigned char)(wv & 0xFF);
            }
        }
        __syncthreads();
        {
            int row = tid >> 2;
            int c16 = (tid & 3) * 16;
            int gr  = row0 + row;
            if (gr < M) {
                int4 v = *reinterpret_cast<const int4*>(&lds8[row][c16]);
                *reinterpret_cast<int4*>(&C8[(size_t)gr * 256 + by * 64 + c16]) = v;
            }
        }
    }
}

// ---------------------------------------------------------------------------
// gemm2: A = h1 (fp16), B = W2 (fp32, staged-converted), output fp8 [M][64]
// (+ fused layer-2 att coefs). Same tile math as before; epilogue packs
// acc -> fp8 via LDS alias (mirror of layer-1's verified STORE_FP8 path).
// ---------------------------------------------------------------------------
__global__ __launch_bounds__(256) void gemm2_kernel(
        const _Float16* __restrict__ A, const float* __restrict__ B,
        unsigned char* __restrict__ C8, const float* __restrict__ att_s,
        const float* __restrict__ att_d, float* __restrict__ a_s,
        float* __restrict__ a_d, int M)
{
    __shared__ _Float16 As[64][72];
    __shared__ _Float16 Bt[64][72];

    const int tid  = threadIdx.x;
    const int row0 = blockIdx.x * 64;

    {   // stage A tile: 64 rows x 64 halves (fp16 in)
        int row = tid >> 2;
        int kc  = (tid & 3) * 16;
        int gr  = row0 + row;
        #pragma unroll
        for (int i = 0; i < 2; i++) {
            half8 v = {};
            if (gr < M)
                v = *reinterpret_cast<const half8*>(&A[(size_t)gr * 64 + kc + i * 8]);
            *reinterpret_cast<half8*>(&As[row][kc + i * 8]) = v;
        }
    }
    {   // stage B transposed: Bt[n][k], fp32 -> fp16
        #pragma unroll
        for (int i = 0; i < 4; i++) {
            int id = tid + 256 * i;
            int k  = id >> 4;
            int n4 = (id & 15) * 4;
            float4 f = *reinterpret_cast<const float4*>(&B[(size_t)k * 64 + n4]);
            Bt[n4 + 0][k] = (_Float16)f.x;
            Bt[n4 + 1][k] = (_Float16)f.y;
            Bt[n4 + 2][k] = (_Float16)f.z;
            Bt[n4 + 3][k] = (_Float16)f.w;
        }
    }
    __syncthreads();

    const int wid  = tid >> 6;
    const int lane = tid & 63;
    const int r    = lane & 15;
    const int quad = lane >> 4;
    const int rw0  = wid * 16;

    floatx4 acc[4] = {};
    #pragma unroll
    for (int s = 0; s < 2; s++) {
        half8 af = *reinterpret_cast<const half8*>(&As[rw0 + r][s * 32 + quad * 8]);
        #pragma unroll
        for (int nt = 0; nt < 4; nt++) {
            half8 bf = *reinterpret_cast<const half8*>(&Bt[nt * 16 + r][s * 32 + quad * 8]);
            acc[nt] = __builtin_amdgcn_mfma_f32_16x16x32_f16(af, bf, acc[nt], 0, 0, 0);
        }
    }

    // ---- fused att-coef: heads 0/1 over column halves (HPB=2, CPH=32) ----
    float ps[2][4], pd[2][4];
    #pragma unroll
    for (int hl = 0; hl < 2; hl++)
        #pragma unroll
        for (int reg = 0; reg < 4; reg++) { ps[hl][reg] = 0.f; pd[hl][reg] = 0.f; }
    #pragma unroll
    for (int nt = 0; nt < 4; nt++) {
        int hl = nt >> 1;                 // nt/NTH, NTH=2
        int cl = (nt & 1) * 16 + r;       // column within head
        float ws = att_s[hl * 32 + cl];
        float wd = att_d[hl * 32 + cl];
        #pragma unroll
        for (int reg = 0; reg < 4; reg++) {
            ps[hl][reg] += acc[nt][reg] * ws;
            pd[hl][reg] += acc[nt][reg] * wd;
        }
    }
    #pragma unroll
    for (int off = 1; off < 16; off <<= 1)
        #pragma unroll
        for (int hl = 0; hl < 2; hl++)
            #pragma unroll
            for (int reg = 0; reg < 4; reg++) {
                ps[hl][reg] += __shfl_xor(ps[hl][reg], off);
                pd[hl][reg] += __shfl_xor(pd[hl][reg], off);
            }
    if (r == 0) {
        #pragma unroll
        for (int reg = 0; reg < 4; reg++) {
            int gr = row0 + rw0 + quad * 4 + reg;
            if (gr < M) {
                #pragma unroll
                for (int hl = 0; hl < 2; hl++) {
                    a_s[gr * 2 + hl] = ps[hl][reg];
                    a_d[gr * 2 + hl] = pd[hl][reg];
                }
            }
        }
    }

    // ---- fp8 pack through As-aliased LDS, coalesced 64B-row stores ----
    __syncthreads();
    unsigned char (*lds8)[80] = reinterpret_cast<unsigned char(*)[80]>(&As[0][0]);
    #pragma unroll
    for (int nt = 0; nt < 4; nt++) {
        #pragma unroll
        for (int reg = 0; reg < 4; reg++) {
            int wv = __builtin_amdgcn_cvt_pk_fp8_f32(
                acc[nt][reg], acc[nt][reg], 0, false);
            lds8[rw0 + quad * 4 + reg][nt * 16 + r] = (unsigned char)(wv & 0xFF);
        }
    }
    __syncthreads();
    {
        int row = tid >> 2;
        int c16 = (tid & 3) * 16;
        int gr  = row0 + row;
        if (gr < M) {
            int4 v = *reinterpret_cast<const int4*>(&lds8[row][c16]);
            *reinterpret_cast<int4*>(&C8[(size_t)gr * 64 + c16]) = v;
        }
    }
}

// ---------------------------------------------------------------------------
// FMA helpers.
// ---------------------------------------------------------------------------
__device__ inline void facc4_h(float* a, float2 raw, float p) {
    __half2 h0 = *reinterpret_cast<__half2*>(&raw.x);
    __half2 h1 = *reinterpret_cast<__half2*>(&raw.y);
    float2 f0 = __half22float2(h0), f1 = __half22float2(h1);
    a[0] += p * f0.x; a[1] += p * f0.y; a[2] += p * f1.x; a[3] += p * f1.y;
}
__device__ inline void facc4_8(float* a, unsigned int w, float p) {
    floatx2 lo = __builtin_amdgcn_cvt_pk_f32_fp8((int)w, false);
    floatx2 hi = __builtin_amdgcn_cvt_pk_f32_fp8((int)w, true);
    a[0] += p * lo[0]; a[1] += p * lo[1]; a[2] += p * hi[0]; a[3] += p * hi[1];
}
__device__ inline void facc8_8(float* a, uint2 w, float p) {
    facc4_8(a,     w.x, p);
    facc4_8(a + 4, w.y, p);
}
__device__ inline float fp8_dec1(unsigned char b) {
    floatx2 lo = __builtin_amdgcn_cvt_pk_f32_fp8((int)(unsigned int)b, false);
    return lo[0];
}

// ---------------------------------------------------------------------------
// General path (32 < deg <= 64, rare): full-wave per-node, max-subtraction.
// FEAT_FP8 supported for both FV==4 (layer1) and FV==1 (layer2).
// ---------------------------------------------------------------------------
template<int H, int C, bool OUT_HALF, bool FEAT_FP8>
__device__ void gat_general(
        int d, int lo, int degc, const int* __restrict__ colidx,
        const void* __restrict__ hfeat_v, const float* __restrict__ a_s,
        const float* __restrict__ a_d, const float* __restrict__ bias,
        void* __restrict__ out_v, int N, float* p_wave)
{
    if (d >= N) return;
    constexpr int FV = (H * C) / 64;
    const int lane = threadIdx.x & 63;
    const int hi = lo + degc;
    const __half* hfeat = (const __half*)hfeat_v;
    const unsigned char* ffeat = (const unsigned char*)hfeat_v;
    const int h_lane = (lane * FV) / C;

    float adp[H];
    #pragma unroll
    for (int h = 0; h < H; h++) adp[h] = a_d[d * H + h];
    float lh[H];
    #pragma unroll
    for (int h = 0; h < H; h++) lh[h] = 0.f;
    float acc[FV];
    #pragma unroll
    for (int v = 0; v < FV; v++) acc[v] = 0.f;

    float mh[H];
    #pragma unroll
    for (int h = 0; h < H; h++) mh[h] = -3.0e38f;
    for (int i = lo + lane; i < hi; i += 64) {
        int s = colidx[i];
        #pragma unroll
        for (int h = 0; h < H; h++) {
            float v = a_s[s * H + h] + adp[h];
            v = (v > 0.f) ? v : 0.2f * v;
            mh[h] = fmaxf(mh[h], v);
        }
    }
    #pragma unroll
    for (int off = 1; off < 64; off <<= 1)
        #pragma unroll
        for (int h = 0; h < H; h++)
            mh[h] = fmaxf(mh[h], __shfl_xor(mh[h], off));

    for (int base = lo; base < hi; base += 64) {
        int i = base + lane;
        int s = 0;
        if (i < hi) {
            s = colidx[i];
            #pragma unroll
            for (int h = 0; h < H; h++) {
                float v = a_s[s * H + h] + adp[h];
                v = (v > 0.f) ? v : 0.2f * v;
                float p = __expf(v - mh[h]);
                lh[h] += p;
                p_wave[(i - base) * H + h] = p;
            }
        }
        int cnt = min(64, hi - base);
        for (int j = 0; j < cnt; j++) {
            int s_j = __shfl(s, j);
            float pj = p_wave[j * H + h_lane];
            if constexpr (FV == 4 && FEAT_FP8) {
                unsigned int raw = *reinterpret_cast<const unsigned int*>(
                    ffeat + (size_t)s_j * (H * C) + lane * 4);
                facc4_8(acc, raw, pj);
            } else if constexpr (FV == 4) {
                float2 raw = *reinterpret_cast<const float2*>(
                    hfeat + (size_t)s_j * (H * C) + lane * 4);
                facc4_h(acc, raw, pj);
            } else if constexpr (FEAT_FP8) {
                acc[0] += pj * fp8_dec1(ffeat[(size_t)s_j * (H * C) + lane]);
            } else {
                acc[0] += pj * __half2float(hfeat[(size_t)s_j * (H * C) + lane]);
            }
        }
    }
    #pragma unroll
    for (int off = 1; off < 64; off <<= 1)
        #pragma unroll
        for (int h = 0; h < H; h++)
            lh[h] += __shfl_xor(lh[h], off);

    float lsel = lh[0];
    #pragma unroll
    for (int h = 1; h < H; h++) if (h_lane == h) lsel = lh[h];
    const float inv = 1.0f / (lsel + 1e-16f);

    if constexpr (FV == 4) {
        float vx = acc[0] * inv, vy = acc[1] * inv,
              vz = acc[2] * inv, vw = acc[3] * inv;
        vx += __shfl_xor(vx, 16); vy += __shfl_xor(vy, 16);
        vz += __shfl_xor(vz, 16); vw += __shfl_xor(vw, 16);
        vx += __shfl_xor(vx, 32); vy += __shfl_xor(vy, 32);
        vz += __shfl_xor(vz, 32); vw += __shfl_xor(vw, 32);
        if (lane < 16) {
            float4 bv = *reinterpret_cast<const float4*>(&bias[lane * 4]);
            float ox = fmaxf(0.25f * vx + bv.x, 0.f);
            float oy = fmaxf(0.25f * vy + bv.y, 0.f);
            float oz = fmaxf(0.25f * vz + bv.z, 0.f);
            float ow = fmaxf(0.25f * vw + bv.w, 0.f);
            if constexpr (OUT_HALF) {
                half4v hv = { (_Float16)ox, (_Float16)oy, (_Float16)oz, (_Float16)ow };
                *reinterpret_cast<half4v*>((_Float16*)out_v + (size_t)d * C + lane * 4) = hv;
            } else {
                float4 o = make_float4(ox, oy, oz, ow);
                *reinterpret_cast<float4*>((float*)out_v + (size_t)d * C + lane * 4) = o;
            }
        }
    } else {
        float v = acc[0] * inv;
        v += __shfl_xor(v, 32);
        if (lane < 32) {
            float o = fmaxf(0.5f * v + bias[lane], 0.f);
            if constexpr (OUT_HALF)
                ((_Float16*)out_v)[(size_t)d * C + lane] = (_Float16)o;
            else
                ((float*)out_v)[(size_t)d * C + lane] = o;
        }
    }
}

// ---------------------------------------------------------------------------
// Fused GAT aggregation over ELL rows, 2 nodes per wave (R17 form).
// degv is the PADDED deg16 array (stride 16 ints).
// H==4: fp8 gather (layer 1).  H==2: fp8 gather when FEAT_FP8 (layer 2).
// ---------------------------------------------------------------------------
template<int H, int C, bool OUT_HALF, bool FEAT_FP8>
__global__ __launch_bounds__(256) void gat_dst(
        const int* __restrict__ degv, const int* __restrict__ col_ell,
        const void* __restrict__ hfeat_v, const float* __restrict__ a_s,
        const float* __restrict__ a_d, const float* __restrict__ bias,
        void* __restrict__ out_v, int N)
{
    const int wid  = threadIdx.x >> 6;
    const int lane = threadIdx.x & 63;
    const int nw   = lane >> 5;          // node-in-wave (0/1)
    const int l32  = lane & 31;

    __shared__ float p_sh[4][64 * H];    // per wave: 2 nodes x 32 edges x H

    const int d  = blockIdx.x * 8 + wid * 2 + nw;
    const bool nodeok = (d < N);
    const int lo = d * 64;               // ELL row base

    int degc = 0;
    if (nodeok) degc = min(degv[d << 4], 64);
    const int degA = __shfl(degc, 0);
    const int degB = __shfl(degc, 32);
    const bool fast = (degA <= 32) && (degB <= 32);

    if (fast) {
        const __half* hfeat = (const __half*)hfeat_v;
        const unsigned char* ffeat = (const unsigned char*)hfeat_v;

        float adp[H];
        #pragma unroll
        for (int h = 0; h < H; h++) adp[h] = nodeok ? a_d[d * H + h] : 0.f;

        // ---- phase A: scores -> p = exp(e) directly (no max-sub) ----
        int s = 0;
        float lh[H];
        #pragma unroll
        for (int h = 0; h < H; h++) lh[h] = 0.f;
        const bool valid = nodeok && (l32 < degc);
        if (valid) {
            s = col_ell[lo + l32];
            if constexpr (H == 4) {
                float4 av = *reinterpret_cast<const float4*>(&a_s[s * 4]);
                float ev[4] = {av.x + adp[0], av.y + adp[1],
                               av.z + adp[2], av.w + adp[3]};
                #pragma unroll
                for (int h = 0; h < 4; h++) {
                    float e = (ev[h] > 0.f) ? ev[h] : 0.2f * ev[h];
                    float p = __expf(e);
                    lh[h] = p;
                    p_sh[wid][nw * 32 * H + l32 * H + h] = p;
                }
            } else {
                float2 av = *reinterpret_cast<const float2*>(&a_s[s * 2]);
                float ev[2] = {av.x + adp[0], av.y + adp[1]};
                #pragma unroll
                for (int h = 0; h < 2; h++) {
                    float e = (ev[h] > 0.f) ? ev[h] : 0.2f * ev[h];
                    float p = __expf(e);
                    lh[h] = p;
                    p_sh[wid][nw * 32 * H + l32 * H + h] = p;
                }
            }
        }
        #pragma unroll
        for (int off = 1; off < 32; off <<= 1)
            #pragma unroll
            for (int h = 0; h < H; h++)
                lh[h] += __shfl_xor(lh[h], off);

        const int sbase = nw * 32;

        if constexpr (H == 4) {
            // ---- L1: 32 lanes x 8B fp8 = full 256B row per edge ----
            const int hl = l32 >> 3;
            float a0[8] = {}, a1[8] = {};
            int j = 0;
            for (; j + 8 <= degc; j += 8) {
                uint2 raw[8]; float pw[8];
                #pragma unroll
                for (int u = 0; u < 8; u++) {
                    int sj = __shfl(s, sbase + j + u);
                    pw[u]  = p_sh[wid][nw * 128 + (j + u) * 4 + hl];
                    raw[u] = *reinterpret_cast<const uint2*>(
                        ffeat + (size_t)sj * 256 + l32 * 8);
                }
                #pragma unroll
                for (int u = 0; u < 8; u++)
                    facc8_8((u & 1) ? a1 : a0, raw[u], pw[u]);
            }
            for (; j < degc; j++) {
                int sj = __shfl(s, sbase + j);
                float pw = p_sh[wid][nw * 128 + j * 4 + hl];
                uint2 raw = *reinterpret_cast<const uint2*>(
                    ffeat + (size_t)sj * 256 + l32 * 8);
                facc8_8(a0, raw, pw);
            }
            #pragma unroll
            for (int k = 0; k < 8; k++) a0[k] += a1[k];

            float lsel = lh[0];
            #pragma unroll
            for (int h = 1; h < 4; h++) if (hl == h) lsel = lh[h];
            float inv = 1.0f / (lsel + 1e-16f);
            #pragma unroll
            for (int k = 0; k < 8; k++) {
                float v = a0[k] * inv;
                v += __shfl_xor(v, 8);       // head-mean (within half)
                v += __shfl_xor(v, 16);
                a0[k] = v;
            }
            if (nodeok && l32 < 8) {
                float4 b0 = *reinterpret_cast<const float4*>(&bias[l32 * 8]);
                float4 b1 = *reinterpret_cast<const float4*>(&bias[l32 * 8 + 4]);
                float bb[8] = {b0.x, b0.y, b0.z, b0.w, b1.x, b1.y, b1.z, b1.w};
                half8 hv;
                #pragma unroll
                for (int k = 0; k < 8; k++)
                    hv[k] = (_Float16)fmaxf(0.25f * a0[k] + bb[k], 0.f);
                *reinterpret_cast<half8*>((_Float16*)out_v + (size_t)d * 64 + l32 * 8) = hv;
            }
        } else {
            // ---- L2: 16 lanes x 4B fp8 = full 64B row, 2 edges/half ----
            const int q   = l32 >> 4;
            const int l16 = l32 & 15;
            const int hl2 = l16 >> 3;
            float a0[4] = {}, a1[4] = {};
            int j = 0;
            for (; j + 8 <= degc; j += 8) {
                unsigned int raw[4]; float pw[4];
                #pragma unroll
                for (int u = 0; u < 4; u++) {
                    int je = j + 2 * u + q;
                    int sj = __shfl(s, sbase + je);
                    pw[u]  = p_sh[wid][nw * 64 + je * 2 + hl2];
                    raw[u] = *reinterpret_cast<const unsigned int*>(
                        ffeat + (size_t)sj * 64 + l16 * 4);
                }
                #pragma unroll
                for (int u = 0; u < 4; u++)
                    facc4_8((u & 1) ? a1 : a0, raw[u], pw[u]);
            }
            for (int jr = j + q; jr < degc; jr += 2) {
                int sj = __shfl(s, sbase + jr);
                float pw = p_sh[wid][nw * 64 + jr * 2 + hl2];
                unsigned int raw = *reinterpret_cast<const unsigned int*>(
                    ffeat + (size_t)sj * 64 + l16 * 4);
                facc4_8(a0, raw, pw);
            }
            #pragma unroll
            for (int k = 0; k < 4; k++) {
                a0[k] += a1[k];
                a0[k] += __shfl_xor(a0[k], 16);   // q-combine within half
            }
            float lsel = (hl2 == 0) ? lh[0] : lh[1];
            float inv = 1.0f / (lsel + 1e-16f);
            #pragma unroll
            for (int k = 0; k < 4; k++) {
                float v = a0[k] * inv;
                v += __shfl_xor(v, 8);            // head-mean
                a0[k] = v;
            }
            if (nodeok && l32 < 8) {
                float4 bb = *reinterpret_cast<const float4*>(&bias[l32 * 4]);
                float4 o;
                o.x = fmaxf(0.5f * a0[0] + bb.x, 0.f);
                o.y = fmaxf(0.5f * a0[1] + bb.y, 0.f);
                o.z = fmaxf(0.5f * a0[2] + bb.z, 0.f);
                o.w = fmaxf(0.5f * a0[3] + bb.w, 0.f);
                *reinterpret_cast<float4*>((float*)out_v + (size_t)d * 32 + l32 * 4) = o;
            }
        }
        return;
    }

    // ---- rare: full-wave general path, each node sequentially ----
    const int dA = blockIdx.x * 8 + wid * 2;
    gat_general<H, C, OUT_HALF, FEAT_FP8>(
        dA, dA * 64, __shfl(degc, 0), col_ell,
        hfeat_v, a_s, a_d, bias, out_v, N, p_sh[wid]);
    gat_general<H, C, OUT_HALF, FEAT_FP8>(
        dA + 1, (dA + 1) * 64, __shfl(degc, 32), col_ell,
        hfeat_v, a_s, a_d, bias, out_v, N, p_sh[wid]);
}

// ---------------------------------------------------------------------------
// Merged pool + heads (R17 form).
// ---------------------------------------------------------------------------
__global__ __launch_bounds__(256) void pool_heads(
        const float* __restrict__ h2, const int* __restrict__ batch,
        const float* __restrict__ cW1, const float* __restrict__ cb1,
        const float* __restrict__ cW2, const float* __restrict__ cb2,
        const float* __restrict__ hW1, const float* __restrict__ hb1,
        const float* __restrict__ hW2, const float* __restrict__ hb2,
        float* __restrict__ out, int N)
{
    const int g = blockIdx.x;
    const int c = threadIdx.x & 31;
    const int r = threadIdx.x >> 5;

    __shared__ int bounds[2];
    __shared__ float red[8][32];
    __shared__ float emb_s[32];
    __shared__ float hidden[32];

    if (threadIdx.x < 2) {
        int target = g + (int)threadIdx.x;
        int lo = 0, hi = N;
        while (lo < hi) {
            int mid = (lo + hi) >> 1;
            if (batch[mid] < target) lo = mid + 1; else hi = mid;
        }
        bounds[threadIdx.x] = lo;
    }
    __syncthreads();
    const int lo = bounds[0], hi = bounds[1];

    float acc = 0.f;
    for (int n = lo + r; n < hi; n += 8)
        acc += h2[(size_t)n * 32 + c];
    red[r][c] = acc;
    __syncthreads();
    if (r == 0) {
        float s = 0.f;
        #pragma unroll
        for (int i = 0; i < 8; i++) s += red[i][c];
        emb_s[c] = s / fmaxf((float)(hi - lo), 1.0f);
    }
    __syncthreads();

    if (threadIdx.x < 32) {
        int j = threadIdx.x & 15;
        bool is_halt = threadIdx.x >= 16;
        const float* w1v = is_halt ? hW1 : cW1;
        const float* b1v = is_halt ? hb1 : cb1;
        const float* w2v = is_halt ? hW2 : cW2;
        float s = b1v[j];
        #pragma unroll
        for (int cc = 0; cc < 32; cc++) s += emb_s[cc] * w1v[cc * 16 + j];
        hidden[threadIdx.x] = fmaxf(s, 0.f) * w2v[j];
    }
    __syncthreads();
    if (threadIdx.x == 0) {
        float sc = cb2[0], sh = hb2[0];
        #pragma unroll
        for (int i = 0; i < 16; i++) { sc += hidden[i]; sh += hidden[16 + i]; }
        out[g]            = 1.0f / (1.0f + __expf(-sh));   // halt
        out[G_GRAPHS + g] = 1.0f / (1.0f + __expf(-sc));   // cont
    }
}

// ---------------------------------------------------------------------------
extern "C" void kernel_launch(void* const* d_in, const int* in_sizes, int n_in,
                              void* d_out, int out_size, void* d_ws, size_t ws_size,
                              hipStream_t stream)
{
    const float* x   = (const float*)d_in[0];
    const int*   ei  = (const int*)  d_in[1];
    const int*   bat = (const int*)  d_in[2];
    const float* W1  = (const float*)d_in[3];
    const float* as1 = (const float*)d_in[4];
    const float* ad1 = (const float*)d_in[5];
    const float* b1  = (const float*)d_in[6];
    const float* W2  = (const float*)d_in[7];
    const float* as2 = (const float*)d_in[8];
    const float* ad2 = (const float*)d_in[9];
    const float* b2  = (const float*)d_in[10];
    const float* cW1 = (const float*)d_in[11];
    const float* cb1 = (const float*)d_in[12];
    const float* cW2 = (const float*)d_in[13];
    const float* cb2 = (const float*)d_in[14];
    const float* hW1 = (const float*)d_in[15];
    const float* hb1 = (const float*)d_in[16];
    const float* hW2 = (const float*)d_in[17];
    const float* hb2 = (const float*)d_in[18];

    const int N    = in_sizes[2];           // 20000
    const int E0   = in_sizes[1] / 2;       // 320000

    // ---- workspace carve (float-granular) ----
    float* w = (float*)d_ws;
    size_t o = 0;
    unsigned char* h1pre_f8 = (unsigned char*)(w + o); o += (size_t)N * 64; // [N,256] fp8
    _Float16* h1_h    = (_Float16*)(w + o); o += (size_t)N * 32;       // [N,64] fp16
    unsigned char* h2pre_f8 = (unsigned char*)(w + o); o += (size_t)N * 16; // [N,64] fp8
    float* a_s1  = w + o; o += (size_t)N * 4;
    float* a_d1  = w + o; o += (size_t)N * 4;
    float* a_s2  = w + o; o += (size_t)N * 2;
    float* a_d2  = w + o; o += (size_t)N * 2;
    float* h2    = w + o; o += (size_t)N * 32;
    int* deg16   = (int*)(w + o); o += (size_t)N * 16;   // 1 counter / 64B line
    int* col_ell = (int*)(w + o); o += (size_t)N * 64;   // ELL, stride 64
    (void)ws_size; (void)n_in; (void)out_size;

    const dim3 blk(256);
    const int eb4 = (E0 + 1023) / 1024;      // ELL blocks, 4 edges/thread
    const int nb8 = (N + 7) / 8;
    const int mb  = (N + 63) / 64;

    // ---- init: deg16 lines = 1 (self-loop reserved), col_ell slot0 = n ----
    const int n4 = N * 4;
    init_deg_ell<<<(n4 + 255) / 256, blk, 0, stream>>>(
        (int4*)deg16, col_ell, N);

    // ---- FUSED: layer-1 GEMM (blocks [0,mb)) + ELL build (rest) ----
    ell_gemm1<<<mb + eb4, blk, 0, stream>>>(
        ei, deg16, col_ell, E0, mb,
        x, W1, h1pre_f8, as1, ad1, a_s1, a_d1, N);

    // ---- layer 1 aggregation (fp8 gather, 2 nodes/wave) ----
    gat_dst<4, 64, true, true><<<nb8, blk, 0, stream>>>(
        deg16, col_ell, h1pre_f8, a_s1, a_d1, b1, h1_h, N);

    // ---- layer 2: GEMM (fp8 out) + aggregation (fp8 gather, 1 line/row) ----
    gemm2_kernel<<<mb, blk, 0, stream>>>(
        h1_h, W2, h2pre_f8, as2, ad2, a_s2, a_d2, N);
    gat_dst<2, 32, false, true><<<nb8, blk, 0, stream>>>(
        deg16, col_ell, h2pre_f8, a_s2, a_d2, b2, h2, N);

    // ---- pool + heads ----
    pool_heads<<<G_GRAPHS, blk, 0, stream>>>(
        h2, bat, cW1, cb1, cW2, cb2, hW1, hb1, hW2, hb2, (float*)d_out, N);
}